// Round 1
// baseline (606.510 us; speedup 1.0000x reference)
//
#include <hip/hip_runtime.h>
#include <stdint.h>

#define EN 64
#define BN 32
#define PN 197
#define DIN 768
#define HH 512
#define RHO_ 4.0f

typedef __attribute__((ext_vector_type(8))) short bf16x8;
typedef __attribute__((ext_vector_type(4))) float f32x4;

__device__ __forceinline__ ushort f2bf(float f){
  unsigned u = __float_as_uint(f);
  u += 0x7FFFu + ((u >> 16) & 1u);
  return (ushort)(u >> 16);
}
__device__ __forceinline__ float bf2f(ushort h){ return __uint_as_float(((unsigned)h) << 16); }

// ---------------- prep: casts + weight transposes ----------------
__global__ __launch_bounds__(256) void prep_kernel(
    const float* __restrict__ etok, const float* __restrict__ mtok,
    const float* __restrict__ ecls,
    const float* __restrict__ Wq, const float* __restrict__ Wk,
    const float* __restrict__ Wv, const float* __restrict__ Wc,
    const float* __restrict__ bq,
    ushort* __restrict__ a_ent, ushort* __restrict__ a_men, ushort* __restrict__ a_cls,
    ushort* __restrict__ Wt, float* __restrict__ bq_s)
{
  const float s = 0.04419417382415922f; // 1/sqrt(512)
  int g = blockIdx.x*256 + threadIdx.x;
  int st = gridDim.x*256;
  for (int i=g; i<(EN*PN*DIN)/4; i+=st){
    float4 v = ((const float4*)etok)[i];
    ushort4 o; o.x=f2bf(v.x); o.y=f2bf(v.y); o.z=f2bf(v.z); o.w=f2bf(v.w);
    ((ushort4*)a_ent)[i] = o;
  }
  for (int i=g; i<(BN*PN*DIN)/4; i+=st){
    float4 v = ((const float4*)mtok)[i];
    ushort4 o; o.x=f2bf(v.x); o.y=f2bf(v.y); o.z=f2bf(v.z); o.w=f2bf(v.w);
    ((ushort4*)a_men)[i] = o;
  }
  for (int i=g; i<(EN*DIN)/4; i+=st){
    float4 v = ((const float4*)ecls)[i];
    ushort4 o; o.x=f2bf(v.x); o.y=f2bf(v.y); o.z=f2bf(v.z); o.w=f2bf(v.w);
    ((ushort4*)a_cls)[i] = o;
  }
  // W [K=768][N=512] -> Wt [4][N=512][K=768] bf16 ; scale Wq by s
  for (int i=g; i<4*HH*DIN; i+=st){
    int mat = i / (HH*DIN);
    int j = i - mat*(HH*DIN);
    int n = j / DIN;
    int kk = j - n*DIN;
    const float* src = (mat==0)?Wq:(mat==1)?Wk:(mat==2)?Wv:Wc;
    float v = src[kk*HH + n];
    if (mat==0) v *= s;
    Wt[i] = f2bf(v);
  }
  for (int i=g; i<HH; i+=st) bq_s[i] = bq[i]*s;
}

// ---------------- projection GEMMs: C = A @ Wt^T + bias ----------------
// op 0: q = a_ent (12608x768), 1: k = a_men (6304), 2: v = a_men, 3: cls_fc = a_cls (64) fp32-out
__global__ __launch_bounds__(256) void gemm_proj(
    const ushort* __restrict__ a_ent, const ushort* __restrict__ a_men, const ushort* __restrict__ a_cls,
    const ushort* __restrict__ Wt,
    const float* __restrict__ bq_s, const float* __restrict__ bk,
    const float* __restrict__ bv, const float* __restrict__ bc,
    ushort* __restrict__ qo, ushort* __restrict__ ko, ushort* __restrict__ vo,
    float* __restrict__ co)
{
  int op = blockIdx.z;
  int M = (op==0)? EN*PN : (op==3)? EN : BN*PN;
  int m0 = blockIdx.x*128;
  if (m0 >= M) return;
  const ushort* A  = (op==0)? a_ent : (op==3)? a_cls : a_men;
  const ushort* Bw = Wt + (size_t)op*HH*DIN;
  const float* bias = (op==0)? bq_s : (op==1)? bk : (op==2)? bv : bc;
  int n0 = blockIdx.y*128;
  int Mm1 = M-1;

  __shared__ ushort As[128*40];   // row stride 40 ushorts (80B) -> conflict-free frag reads
  __shared__ ushort Bs[128*40];
  int tid = threadIdx.x;
  int lane = tid & 63, wid = tid >> 6;
  int l15 = lane & 15, lg = lane >> 4;
  int wm = wid >> 1, wn = wid & 1;

  f32x4 acc[16];
  #pragma unroll
  for (int i=0;i<16;++i){ f32x4 z = {0.f,0.f,0.f,0.f}; acc[i] = z; }

  bf16x8 sA[2], sB[2];
  #pragma unroll
  for (int i=0;i<2;++i){
    int u = tid + i*256; int row = u>>2; int ko8 = (u&3)*8;
    int rA = m0+row; rA = rA>Mm1 ? Mm1 : rA;
    sA[i] = *(const bf16x8*)(A  + (size_t)rA*DIN + ko8);
    sB[i] = *(const bf16x8*)(Bw + (size_t)(n0+row)*DIN + ko8);
  }
  for (int kt=0; kt<DIN/32; ++kt){
    #pragma unroll
    for (int i=0;i<2;++i){
      int u = tid + i*256; int row = u>>2; int ko8 = (u&3)*8;
      *(bf16x8*)(&As[row*40 + ko8]) = sA[i];
      *(bf16x8*)(&Bs[row*40 + ko8]) = sB[i];
    }
    __syncthreads();
    if (kt < DIN/32 - 1){
      int k0 = (kt+1)*32;
      #pragma unroll
      for (int i=0;i<2;++i){
        int u = tid + i*256; int row = u>>2; int ko8 = (u&3)*8;
        int rA = m0+row; rA = rA>Mm1 ? Mm1 : rA;
        sA[i] = *(const bf16x8*)(A  + (size_t)rA*DIN + k0 + ko8);
        sB[i] = *(const bf16x8*)(Bw + (size_t)(n0+row)*DIN + k0 + ko8);
      }
    }
    bf16x8 af[4], bfg[4];
    #pragma unroll
    for (int t=0;t<4;++t){
      af[t]  = *(const bf16x8*)(&As[(wm*64 + t*16 + l15)*40 + lg*8]);
      bfg[t] = *(const bf16x8*)(&Bs[(wn*64 + t*16 + l15)*40 + lg*8]);
    }
    #pragma unroll
    for (int am=0; am<4; ++am)
      #pragma unroll
      for (int bn=0; bn<4; ++bn)
        acc[am*4+bn] = __builtin_amdgcn_mfma_f32_16x16x32_bf16(af[am], bfg[bn], acc[am*4+bn], 0, 0, 0);
    __syncthreads();
  }

  #pragma unroll
  for (int bn=0; bn<4; ++bn){
    int col = n0 + wn*64 + bn*16 + l15;
    float bval = bias[col];
    #pragma unroll
    for (int am=0; am<4; ++am){
      #pragma unroll
      for (int r=0;r<4;++r){
        int row = m0 + wm*64 + am*16 + lg*4 + r;
        if (row < M){
          float v = acc[am*4+bn][r] + bval;
          if (op==3)      co[(size_t)row*HH + col] = v;
          else if (op==0) qo[(size_t)row*HH + col] = f2bf(v);
          else if (op==1) ko[(size_t)row*HH + col] = f2bf(v);
          else            vo[(size_t)row*HH + col] = f2bf(v);
        }
      }
    }
  }
}

// ---------------- fused attention + column-sum + LN + dots ----------------
// block = (b, e-pair). 4 waves; wave owns a 16-row q-tile, computes S rows for BOTH e's
// (shared B-frag reads). w[q'] = sum_p probs accumulated in LDS; then ctx = w@v/P, LN, dots.
__global__ __launch_bounds__(256) void attn_kernel(
    const ushort* __restrict__ qw, const ushort* __restrict__ kw, const ushort* __restrict__ vw,
    const float* __restrict__ cls_fc, const float* __restrict__ maskp,
    const float* __restrict__ mcls, const float* __restrict__ ecls,
    const float* __restrict__ lng, const float* __restrict__ lnb,
    float* __restrict__ outp)
{
  int bid = blockIdx.x;
  int b = bid >> 5;            // consecutive blocks share b -> k/v L2-hot
  int e0 = (bid & 31) * 2;

  __shared__ ushort klds[32*256];    // 32 cols x 256 k, XOR-swizzled 16B units
  __shared__ float w_lds[2][208];
  __shared__ float red[16];

  int tid = threadIdx.x;
  int lane = tid & 63, wid = tid >> 6;
  int l15 = lane & 15, lg = lane >> 4;

  for (int i=tid; i<416; i+=256) ((float*)w_lds)[i] = 0.f;

  const ushort* kb = kw + (size_t)b*PN*HH;

  for (int rnd=0; rnd<4; ++rnd){
    int tt = rnd*4 + wid;          // row-tile id, 13 tiles of 16 rows (208 >= 197)
    bool active = tt < 13;
    int rt = active ? tt : 12;
    int arow = rt*16 + l15;
    int arowg = arow > 196 ? 196 : arow;

    f32x4 acc[2][13];
    #pragma unroll
    for (int e2=0;e2<2;++e2)
      #pragma unroll
      for (int i=0;i<13;++i){ f32x4 z={0.f,0.f,0.f,0.f}; acc[e2][i]=z; }

    #pragma unroll
    for (int kh=0; kh<2; ++kh){    // k-halves of 256
      bf16x8 afr[2][8];
      if (active){
        #pragma unroll
        for (int e2=0;e2<2;++e2)
          #pragma unroll
          for (int lc=0; lc<8; ++lc)
            afr[e2][lc] = *(const bf16x8*)(qw + (size_t)(e0+e2)*PN*HH + (size_t)arowg*HH + kh*256 + lc*32 + lg*8);
      }
      bf16x8 stg[4];
      // prologue: stage chunk 0
      #pragma unroll
      for (int i=0;i<4;++i){
        int u = tid + i*256;
        int col = (u>>5); int o32 = u&31;
        int cg = col > 196 ? 196 : col;
        stg[i] = *(const bf16x8*)(kb + (size_t)cg*HH + kh*256 + o32*8);
      }
      #pragma unroll
      for (int i=0;i<4;++i){
        int u = tid + i*256;
        int col = (u>>5); int o32 = u&31;
        *(bf16x8*)(&klds[col*256 + ((o32 ^ (col&7))*8)]) = stg[i];
      }
      __syncthreads();
      #pragma unroll
      for (int cc=0; cc<7; ++cc){  // 7 col-chunks of 32
        if (cc < 6){
          int c0 = (cc+1)*32;
          #pragma unroll
          for (int i=0;i<4;++i){
            int u = tid + i*256;
            int col = c0 + (u>>5); int o32 = u&31;
            int cg = col > 196 ? 196 : col;
            stg[i] = *(const bf16x8*)(kb + (size_t)cg*HH + kh*256 + o32*8);
          }
        }
        if (active){
          #pragma unroll
          for (int ct2=0; ct2<2; ++ct2){
            int ct = cc*2 + ct2;
            if (ct < 13){
              int col = ct2*16 + l15;
              #pragma unroll
              for (int lc=0; lc<8; ++lc){
                bf16x8 bfr = *(const bf16x8*)(&klds[col*256 + (((lc*4+lg) ^ (col&7))*8)]);
                acc[0][ct] = __builtin_amdgcn_mfma_f32_16x16x32_bf16(afr[0][lc], bfr, acc[0][ct], 0,0,0);
                acc[1][ct] = __builtin_amdgcn_mfma_f32_16x16x32_bf16(afr[1][lc], bfr, acc[1][ct], 0,0,0);
              }
            }
          }
        }
        __syncthreads();
        if (cc < 6){
          #pragma unroll
          for (int i=0;i<4;++i){
            int u = tid + i*256;
            int col = (u>>5); int o32 = u&31;
            *(bf16x8*)(&klds[col*256 + ((o32 ^ (col&7))*8)]) = stg[i];
          }
          __syncthreads();
        }
      }
    }

    if (active){
      #pragma unroll
      for (int e2=0; e2<2; ++e2){
        // invalidate padded cols 197..207 (tile 12, l15>=5)
        if (l15 >= 5){
          f32x4 ninf = {-1e30f,-1e30f,-1e30f,-1e30f};
          acc[e2][12] = ninf;
        }
        // additive mask on query-row 0 only (C layout: row = lg*4+r, col = ct*16+l15)
        if (rt==0 && lg==0){
          #pragma unroll
          for (int ct=0; ct<13; ++ct){
            int col = ct*16 + l15;
            if (col < 197) acc[e2][ct][0] += RHO_ * maskp[b*PN + col];
          }
        }
        float mrow[4], inv[4];
        #pragma unroll
        for (int r=0;r<4;++r){
          float m = acc[e2][0][r];
          #pragma unroll
          for (int ct=1; ct<13; ++ct) m = fmaxf(m, acc[e2][ct][r]);
          m = fmaxf(m, __shfl_xor(m,1));
          m = fmaxf(m, __shfl_xor(m,2));
          m = fmaxf(m, __shfl_xor(m,4));
          m = fmaxf(m, __shfl_xor(m,8));
          mrow[r] = m;
        }
        #pragma unroll
        for (int r=0;r<4;++r){
          float s = 0.f;
          #pragma unroll
          for (int ct=0; ct<13; ++ct){
            float ev = __expf(acc[e2][ct][r] - mrow[r]);
            acc[e2][ct][r] = ev;
            s += ev;
          }
          s += __shfl_xor(s,1); s += __shfl_xor(s,2);
          s += __shfl_xor(s,4); s += __shfl_xor(s,8);
          int prow = rt*16 + lg*4 + r;
          inv[r] = (prow < PN) ? 1.0f/s : 0.f;   // exclude padded rows
        }
        #pragma unroll
        for (int ct=0; ct<13; ++ct){
          float cs = acc[e2][ct][0]*inv[0] + acc[e2][ct][1]*inv[1]
                   + acc[e2][ct][2]*inv[2] + acc[e2][ct][3]*inv[3];
          cs += __shfl_xor(cs,16);
          cs += __shfl_xor(cs,32);
          if (lg==0) atomicAdd(&w_lds[e2][ct*16 + l15], cs);
        }
      }
    }
  }
  __syncthreads();

  // phase 2: ctx[h] = (1/197) * sum_q w[q]*v[b,q,h]; thread owns h=2t,2t+1 for both e's
  const ushort* vb = vw + (size_t)b*PN*HH;
  float cA0=0.f, cA1=0.f, cB0=0.f, cB1=0.f;
  #pragma unroll 4
  for (int q=0; q<PN; ++q){
    unsigned vv = *(const unsigned*)(vb + (size_t)q*HH + 2*tid);
    float v0 = bf2f((ushort)(vv & 0xffffu));
    float v1 = bf2f((ushort)(vv >> 16));
    float w0 = w_lds[0][q], w1 = w_lds[1][q];
    cA0 += w0*v0; cA1 += w0*v1;
    cB0 += w1*v0; cB1 += w1*v1;
  }
  const float invP = 1.0f/197.0f;
  cA0*=invP; cA1*=invP; cB0*=invP; cB1*=invP;

  float sx = cA0+cA1, sxx = cA0*cA0+cA1*cA1;
  float sy = cB0+cB1, syy = cB0*cB0+cB1*cB1;
  #pragma unroll
  for (int off=32; off; off>>=1){
    sx += __shfl_down(sx, off); sxx += __shfl_down(sxx, off);
    sy += __shfl_down(sy, off); syy += __shfl_down(syy, off);
  }
  if (lane==0){ red[wid*4+0]=sx; red[wid*4+1]=sxx; red[wid*4+2]=sy; red[wid*4+3]=syy; }
  __syncthreads();
  float s1A = red[0]+red[4]+red[8]+red[12];
  float s2A = red[1]+red[5]+red[9]+red[13];
  float s1B = red[2]+red[6]+red[10]+red[14];
  float s2B = red[3]+red[7]+red[11]+red[15];
  float muA = s1A*(1.f/512.f), muB = s1B*(1.f/512.f);
  float varA = s2A*(1.f/512.f) - muA*muA;
  float varB = s2B*(1.f/512.f) - muB*muB;
  float rsA = rsqrtf(varA + 1e-5f), rsB = rsqrtf(varB + 1e-5f);

  int h0 = 2*tid, h1 = 2*tid+1;
  float g0=lng[h0], g1=lng[h1], bb0=lnb[h0], bb1=lnb[h1];
  float fA0 = cls_fc[(size_t)e0*HH + h0],     fA1 = cls_fc[(size_t)e0*HH + h1];
  float fB0 = cls_fc[(size_t)(e0+1)*HH + h0], fB1 = cls_fc[(size_t)(e0+1)*HH + h1];
  float dA = ((cA0-muA)*rsA*g0 + bb0)*fA0 + ((cA1-muA)*rsA*g1 + bb1)*fA1;
  float dB = ((cB0-muB)*rsB*g0 + bb0)*fB0 + ((cB1-muB)*rsB*g1 + bb1)*fB1;

  // g2g partial: 3 dims per thread (768 = 256*3)
  int j = 3*tid;
  float m0v = mcls[b*DIN + j], m1v = mcls[b*DIN + j+1], m2v = mcls[b*DIN + j+2];
  dA += m0v*ecls[(size_t)e0*DIN + j] + m1v*ecls[(size_t)e0*DIN + j+1] + m2v*ecls[(size_t)e0*DIN + j+2];
  dB += m0v*ecls[(size_t)(e0+1)*DIN + j] + m1v*ecls[(size_t)(e0+1)*DIN + j+1] + m2v*ecls[(size_t)(e0+1)*DIN + j+2];

  __syncthreads();
  #pragma unroll
  for (int off=32; off; off>>=1){ dA += __shfl_down(dA, off); dB += __shfl_down(dB, off); }
  if (lane==0){ red[wid*2+0]=dA; red[wid*2+1]=dB; }
  __syncthreads();
  if (tid==0){
    outp[b*EN + e0]   = 0.5f*(red[0]+red[2]+red[4]+red[6]);
    outp[b*EN + e0+1] = 0.5f*(red[1]+red[3]+red[5]+red[7]);
  }
}

extern "C" void kernel_launch(void* const* d_in, const int* in_sizes, int n_in,
                              void* d_out, int out_size, void* d_ws, size_t ws_size,
                              hipStream_t stream)
{
  (void)in_sizes; (void)n_in; (void)out_size; (void)ws_size;
  const float* ecls = (const float*)d_in[0];
  const float* etok = (const float*)d_in[1];
  const float* mcls = (const float*)d_in[2];
  const float* mtok = (const float*)d_in[3];
  const float* maskp= (const float*)d_in[4];
  const float* Wq   = (const float*)d_in[5];
  const float* bq   = (const float*)d_in[6];
  const float* Wk   = (const float*)d_in[7];
  const float* bk   = (const float*)d_in[8];
  const float* Wv   = (const float*)d_in[9];
  const float* bv   = (const float*)d_in[10];
  const float* Wc   = (const float*)d_in[11];
  const float* bc   = (const float*)d_in[12];
  const float* lng  = (const float*)d_in[13];
  const float* lnb  = (const float*)d_in[14];

  char* ws = (char*)d_ws;
  size_t off = 0;
  auto take = [&](size_t bytes){ char* p = ws + off; off += (bytes + 255) & ~(size_t)255; return p; };
  ushort* a_ent = (ushort*)take((size_t)EN*PN*DIN*2);
  ushort* a_men = (ushort*)take((size_t)BN*PN*DIN*2);
  ushort* a_cls = (ushort*)take((size_t)EN*DIN*2);
  ushort* Wt    = (ushort*)take((size_t)4*HH*DIN*2);
  float*  bq_s  = (float*)take((size_t)HH*4);
  ushort* qo    = (ushort*)take((size_t)EN*PN*HH*2);
  ushort* ko    = (ushort*)take((size_t)BN*PN*HH*2);
  ushort* vo    = (ushort*)take((size_t)BN*PN*HH*2);
  float*  co    = (float*)take((size_t)EN*HH*4);

  prep_kernel<<<2048, 256, 0, stream>>>(etok, mtok, ecls, Wq, Wk, Wv, Wc, bq,
                                        a_ent, a_men, a_cls, Wt, bq_s);
  gemm_proj<<<dim3(99,4,4), 256, 0, stream>>>(a_ent, a_men, a_cls, Wt,
                                              bq_s, bk, bv, bc, qo, ko, vo, co);
  attn_kernel<<<1024, 256, 0, stream>>>(qo, ko, vo, co, maskp, mcls, ecls,
                                        lng, lnb, (float*)d_out);
}

// Round 2
// 557.319 us; speedup vs baseline: 1.0883x; 1.0883x over previous
//
#include <hip/hip_runtime.h>
#include <stdint.h>

#define EN 64
#define BN 32
#define PN 197
#define DIN 768
#define HH 512
#define RHO_ 4.0f

typedef __attribute__((ext_vector_type(8))) short bf16x8;
typedef __attribute__((ext_vector_type(4))) float f32x4;

__device__ __forceinline__ ushort f2bf(float f){
  unsigned u = __float_as_uint(f);
  u += 0x7FFFu + ((u >> 16) & 1u);
  return (ushort)(u >> 16);
}
__device__ __forceinline__ float bf2f(ushort h){ return __uint_as_float(((unsigned)h) << 16); }

// ---------------- prep: casts + weight transposes ----------------
__global__ __launch_bounds__(256) void prep_kernel(
    const float* __restrict__ etok, const float* __restrict__ mtok,
    const float* __restrict__ ecls,
    const float* __restrict__ Wq, const float* __restrict__ Wk,
    const float* __restrict__ Wv, const float* __restrict__ Wc,
    const float* __restrict__ bq,
    ushort* __restrict__ a_ent, ushort* __restrict__ a_men, ushort* __restrict__ a_cls,
    ushort* __restrict__ Wt, float* __restrict__ bq_s)
{
  const float s = 0.04419417382415922f; // 1/sqrt(512)
  int g = blockIdx.x*256 + threadIdx.x;
  int st = gridDim.x*256;
  for (int i=g; i<(EN*PN*DIN)/4; i+=st){
    float4 v = ((const float4*)etok)[i];
    ushort4 o; o.x=f2bf(v.x); o.y=f2bf(v.y); o.z=f2bf(v.z); o.w=f2bf(v.w);
    ((ushort4*)a_ent)[i] = o;
  }
  for (int i=g; i<(BN*PN*DIN)/4; i+=st){
    float4 v = ((const float4*)mtok)[i];
    ushort4 o; o.x=f2bf(v.x); o.y=f2bf(v.y); o.z=f2bf(v.z); o.w=f2bf(v.w);
    ((ushort4*)a_men)[i] = o;
  }
  for (int i=g; i<(EN*DIN)/4; i+=st){
    float4 v = ((const float4*)ecls)[i];
    ushort4 o; o.x=f2bf(v.x); o.y=f2bf(v.y); o.z=f2bf(v.z); o.w=f2bf(v.w);
    ((ushort4*)a_cls)[i] = o;
  }
  // W [K=768][N=512] -> Wt [4][N=512][K=768] bf16 ; scale Wq by s
  for (int i=g; i<4*HH*DIN; i+=st){
    int mat = i / (HH*DIN);
    int j = i - mat*(HH*DIN);
    int n = j / DIN;
    int kk = j - n*DIN;
    const float* src = (mat==0)?Wq:(mat==1)?Wk:(mat==2)?Wv:Wc;
    float v = src[kk*HH + n];
    if (mat==0) v *= s;
    Wt[i] = f2bf(v);
  }
  for (int i=g; i<HH; i+=st) bq_s[i] = bq[i]*s;
}

// ---------------- projection GEMMs: C = A @ Wt^T + bias ----------------
__global__ __launch_bounds__(256) void gemm_proj(
    const ushort* __restrict__ a_ent, const ushort* __restrict__ a_men, const ushort* __restrict__ a_cls,
    const ushort* __restrict__ Wt,
    const float* __restrict__ bq_s, const float* __restrict__ bk,
    const float* __restrict__ bv, const float* __restrict__ bc,
    ushort* __restrict__ qo, ushort* __restrict__ ko, ushort* __restrict__ vo,
    float* __restrict__ co)
{
  // compact block list: 99 tiles op0 (q), 50 op1 (k), 50 op2 (v), 1 op3 (cls)
  int x = blockIdx.x;
  int op, mt;
  if (x < 99)        { op = 0; mt = x; }
  else if (x < 149)  { op = 1; mt = x - 99; }
  else if (x < 199)  { op = 2; mt = x - 149; }
  else               { op = 3; mt = 0; }
  int M = (op==0)? EN*PN : (op==3)? EN : BN*PN;
  int m0 = mt*128;
  const ushort* A  = (op==0)? a_ent : (op==3)? a_cls : a_men;
  const ushort* Bw = Wt + (size_t)op*HH*DIN;
  const float* bias = (op==0)? bq_s : (op==1)? bk : (op==2)? bv : bc;
  int n0 = blockIdx.y*128;
  int Mm1 = M-1;

  __shared__ ushort As[128*40];
  __shared__ ushort Bs[128*40];
  int tid = threadIdx.x;
  int lane = tid & 63, wid = tid >> 6;
  int l15 = lane & 15, lg = lane >> 4;
  int wm = wid >> 1, wn = wid & 1;

  f32x4 acc[16];
  #pragma unroll
  for (int i=0;i<16;++i){ f32x4 z = {0.f,0.f,0.f,0.f}; acc[i] = z; }

  bf16x8 sA[2], sB[2];
  #pragma unroll
  for (int i=0;i<2;++i){
    int u = tid + i*256; int row = u>>2; int ko8 = (u&3)*8;
    int rA = m0+row; rA = rA>Mm1 ? Mm1 : rA;
    sA[i] = *(const bf16x8*)(A  + (size_t)rA*DIN + ko8);
    sB[i] = *(const bf16x8*)(Bw + (size_t)(n0+row)*DIN + ko8);
  }
  for (int kt=0; kt<DIN/32; ++kt){
    #pragma unroll
    for (int i=0;i<2;++i){
      int u = tid + i*256; int row = u>>2; int ko8 = (u&3)*8;
      *(bf16x8*)(&As[row*40 + ko8]) = sA[i];
      *(bf16x8*)(&Bs[row*40 + ko8]) = sB[i];
    }
    __syncthreads();
    if (kt < DIN/32 - 1){
      int k0 = (kt+1)*32;
      #pragma unroll
      for (int i=0;i<2;++i){
        int u = tid + i*256; int row = u>>2; int ko8 = (u&3)*8;
        int rA = m0+row; rA = rA>Mm1 ? Mm1 : rA;
        sA[i] = *(const bf16x8*)(A  + (size_t)rA*DIN + k0 + ko8);
        sB[i] = *(const bf16x8*)(Bw + (size_t)(n0+row)*DIN + k0 + ko8);
      }
    }
    bf16x8 af[4], bfg[4];
    #pragma unroll
    for (int t=0;t<4;++t){
      af[t]  = *(const bf16x8*)(&As[(wm*64 + t*16 + l15)*40 + lg*8]);
      bfg[t] = *(const bf16x8*)(&Bs[(wn*64 + t*16 + l15)*40 + lg*8]);
    }
    #pragma unroll
    for (int am=0; am<4; ++am)
      #pragma unroll
      for (int bn=0; bn<4; ++bn)
        acc[am*4+bn] = __builtin_amdgcn_mfma_f32_16x16x32_bf16(af[am], bfg[bn], acc[am*4+bn], 0, 0, 0);
    __syncthreads();
  }

  #pragma unroll
  for (int bn=0; bn<4; ++bn){
    int col = n0 + wn*64 + bn*16 + l15;
    float bval = bias[col];
    #pragma unroll
    for (int am=0; am<4; ++am){
      #pragma unroll
      for (int r=0;r<4;++r){
        int row = m0 + wm*64 + am*16 + lg*4 + r;
        if (row < M){
          float v = acc[am*4+bn][r] + bval;
          if (op==3)      co[(size_t)row*HH + col] = v;
          else if (op==0) qo[(size_t)row*HH + col] = f2bf(v);
          else if (op==1) ko[(size_t)row*HH + col] = f2bf(v);
          else            vo[(size_t)row*HH + col] = f2bf(v);
        }
      }
    }
  }
}

// ---------------- fused attention: 512 thr, dbuf 112-col chunks ----------------
// block = (b, e-pair); 8 waves, wave owns 16 q-rows, 2 row-passes (13 tiles).
// k staged per (kh, col-half) in double-buffered LDS; loads issued 1 chunk ahead.
__global__ __launch_bounds__(512, 2) void attn_kernel(
    const ushort* __restrict__ qw, const ushort* __restrict__ kw, const ushort* __restrict__ vw,
    const float* __restrict__ cls_fc, const float* __restrict__ maskp,
    const float* __restrict__ mcls, const float* __restrict__ ecls,
    const float* __restrict__ lng, const float* __restrict__ lnb,
    float* __restrict__ outp)
{
  int bid = blockIdx.x;
  int b = bid >> 5;
  int e0 = (bid & 31) * 2;

  __shared__ ushort klds[2][112*256];   // [buf][local_col][k 256], 16B-unit XOR swizzle
  __shared__ float w_lds[2][208];
  __shared__ float red[32];

  int tid = threadIdx.x;
  int lane = tid & 63, wid = tid >> 6;
  int l15 = lane & 15, lg = (lane >> 4) & 3;

  for (int i=tid; i<416; i+=512) ((float*)w_lds)[i] = 0.f;

  const ushort* kb  = kw + (size_t)b*PN*HH;
  const ushort* qb0 = qw + (size_t)e0*PN*HH;
  const ushort* qb1 = qw + (size_t)(e0+1)*PN*HH;

  bf16x8 stg[7];
  bf16x8 afr[2][8];

  for (int rnd=0; rnd<2; ++rnd){
    int tt = rnd*8 + wid;
    bool active = tt < 13;
    int rt = active ? tt : 12;
    int arow = rt*16 + l15;
    int arowg = arow > 196 ? 196 : arow;

    f32x4 acc[2][13];
    #pragma unroll
    for (int e2=0;e2<2;++e2)
      #pragma unroll
      for (int i=0;i<13;++i){ f32x4 z={0.f,0.f,0.f,0.f}; acc[e2][i]=z; }

    // prologue: issue loads for chunk 0 (kh=0, col-half 0)
    #pragma unroll
    for (int i=0;i<7;++i){
      int u = tid + i*512; int col = u>>5, o32 = u&31;
      int cg = col > 196 ? 196 : col;
      stg[i] = *(const bf16x8*)(kb + (size_t)cg*HH + o32*8);
    }

    for (int c=0; c<4; ++c){
      int kh = c>>1, ch = c&1;
      __syncthreads();                       // prev compute done with buf[ch]
      #pragma unroll
      for (int i=0;i<7;++i){                 // stg -> buf[ch] (swizzled)
        int u = tid + i*512; int col = u>>5, o32 = u&31;
        *(bf16x8*)(&klds[ch][col*256 + ((o32 ^ (col&7))*8)]) = stg[i];
      }
      __syncthreads();                       // buf[ch] ready
      if (c < 3){                            // issue next chunk's loads (hidden under MFMA)
        int nkh = (c+1)>>1, ncb = ((c+1)&1)*112;
        #pragma unroll
        for (int i=0;i<7;++i){
          int u = tid + i*512; int col = u>>5, o32 = u&31;
          int cg = ncb + col; cg = cg > 196 ? 196 : cg;
          stg[i] = *(const bf16x8*)(kb + (size_t)cg*HH + nkh*256 + o32*8);
        }
      }
      if (ch == 0 && active){                // fresh kh: load q fragments
        #pragma unroll
        for (int lc=0; lc<8; ++lc){
          afr[0][lc] = *(const bf16x8*)(qb0 + (size_t)arowg*HH + kh*256 + lc*32 + lg*8);
          afr[1][lc] = *(const bf16x8*)(qb1 + (size_t)arowg*HH + kh*256 + lc*32 + lg*8);
        }
      }
      if (active){
        if (ch == 0){
          #pragma unroll
          for (int ct=0; ct<7; ++ct){
            int lcol = ct*16 + l15, sw = lcol & 7;
            #pragma unroll
            for (int lc=0; lc<8; ++lc){
              bf16x8 bfr = *(const bf16x8*)(&klds[0][lcol*256 + (((lc*4+lg) ^ sw)*8)]);
              acc[0][ct] = __builtin_amdgcn_mfma_f32_16x16x32_bf16(afr[0][lc], bfr, acc[0][ct], 0,0,0);
              acc[1][ct] = __builtin_amdgcn_mfma_f32_16x16x32_bf16(afr[1][lc], bfr, acc[1][ct], 0,0,0);
            }
          }
        } else {
          #pragma unroll
          for (int ct=0; ct<6; ++ct){        // tiles 7..12 (cols 112..207)
            int lcol = ct*16 + l15, sw = lcol & 7;
            #pragma unroll
            for (int lc=0; lc<8; ++lc){
              bf16x8 bfr = *(const bf16x8*)(&klds[1][lcol*256 + (((lc*4+lg) ^ sw)*8)]);
              acc[0][7+ct] = __builtin_amdgcn_mfma_f32_16x16x32_bf16(afr[0][lc], bfr, acc[0][7+ct], 0,0,0);
              acc[1][7+ct] = __builtin_amdgcn_mfma_f32_16x16x32_bf16(afr[1][lc], bfr, acc[1][7+ct], 0,0,0);
            }
          }
        }
      }
    }

    if (active){
      #pragma unroll
      for (int e2=0; e2<2; ++e2){
        if (l15 >= 5){                       // cols 197..207 invalid
          f32x4 ninf = {-1e30f,-1e30f,-1e30f,-1e30f};
          acc[e2][12] = ninf;
        }
        if (rt==0 && lg==0){                 // additive mask on query-row 0
          #pragma unroll
          for (int ct=0; ct<13; ++ct){
            int col = ct*16 + l15;
            if (col < 197) acc[e2][ct][0] += RHO_ * maskp[b*PN + col];
          }
        }
        float mrow[4], inv[4];
        #pragma unroll
        for (int r=0;r<4;++r){
          float m = acc[e2][0][r];
          #pragma unroll
          for (int ct=1; ct<13; ++ct) m = fmaxf(m, acc[e2][ct][r]);
          m = fmaxf(m, __shfl_xor(m,1));
          m = fmaxf(m, __shfl_xor(m,2));
          m = fmaxf(m, __shfl_xor(m,4));
          m = fmaxf(m, __shfl_xor(m,8));
          mrow[r] = m;
        }
        #pragma unroll
        for (int r=0;r<4;++r){
          float s = 0.f;
          #pragma unroll
          for (int ct=0; ct<13; ++ct){
            float ev = __expf(acc[e2][ct][r] - mrow[r]);
            acc[e2][ct][r] = ev;
            s += ev;
          }
          s += __shfl_xor(s,1); s += __shfl_xor(s,2);
          s += __shfl_xor(s,4); s += __shfl_xor(s,8);
          int prow = rt*16 + lg*4 + r;
          inv[r] = (prow < PN) ? 1.0f/s : 0.f;
        }
        #pragma unroll
        for (int ct=0; ct<13; ++ct){
          float cs = acc[e2][ct][0]*inv[0] + acc[e2][ct][1]*inv[1]
                   + acc[e2][ct][2]*inv[2] + acc[e2][ct][3]*inv[3];
          cs += __shfl_xor(cs,16);
          cs += __shfl_xor(cs,32);
          if (lg==0) atomicAdd(&w_lds[e2][ct*16 + l15], cs);
        }
      }
    }
  }
  __syncthreads();

  // phase 2: ctx[h] = (1/197) * sum_q w[q]*v[b,q,h]; thread owns h = tid
  const ushort* vb = vw + (size_t)b*PN*HH;
  float cA=0.f, cB=0.f;
  #pragma unroll 4
  for (int q=0; q<PN; ++q){
    float vq = bf2f(vb[(size_t)q*HH + tid]);
    cA += w_lds[0][q]*vq;
    cB += w_lds[1][q]*vq;
  }
  const float invP = 1.0f/197.0f;
  cA*=invP; cB*=invP;

  float sx = cA, sxx = cA*cA, sy = cB, syy = cB*cB;
  #pragma unroll
  for (int off=32; off; off>>=1){
    sx += __shfl_down(sx, off); sxx += __shfl_down(sxx, off);
    sy += __shfl_down(sy, off); syy += __shfl_down(syy, off);
  }
  if (lane==0){ red[wid*4+0]=sx; red[wid*4+1]=sxx; red[wid*4+2]=sy; red[wid*4+3]=syy; }
  __syncthreads();
  float s1A=0.f, s2A=0.f, s1B=0.f, s2B=0.f;
  #pragma unroll
  for (int w=0; w<8; ++w){
    s1A += red[w*4+0]; s2A += red[w*4+1];
    s1B += red[w*4+2]; s2B += red[w*4+3];
  }
  float muA = s1A*(1.f/512.f), muB = s1B*(1.f/512.f);
  float varA = s2A*(1.f/512.f) - muA*muA;
  float varB = s2B*(1.f/512.f) - muB*muB;
  float rsA = rsqrtf(varA + 1e-5f), rsB = rsqrtf(varB + 1e-5f);

  int h = tid;
  float g0=lng[h], bb0=lnb[h];
  float dA = ((cA-muA)*rsA*g0 + bb0) * cls_fc[(size_t)e0*HH + h];
  float dB = ((cB-muB)*rsB*g0 + bb0) * cls_fc[(size_t)(e0+1)*HH + h];

  // g2g: 768 dims over 512 threads (tid; tid+512 for tid<256)
  dA += mcls[b*DIN + tid]*ecls[(size_t)e0*DIN + tid];
  dB += mcls[b*DIN + tid]*ecls[(size_t)(e0+1)*DIN + tid];
  if (tid < 256){
    int j = tid + 512;
    dA += mcls[b*DIN + j]*ecls[(size_t)e0*DIN + j];
    dB += mcls[b*DIN + j]*ecls[(size_t)(e0+1)*DIN + j];
  }

  __syncthreads();
  #pragma unroll
  for (int off=32; off; off>>=1){ dA += __shfl_down(dA, off); dB += __shfl_down(dB, off); }
  if (lane==0){ red[wid*2+0]=dA; red[wid*2+1]=dB; }
  __syncthreads();
  if (tid==0){
    float oA=0.f, oB=0.f;
    #pragma unroll
    for (int w=0; w<8; ++w){ oA += red[w*2+0]; oB += red[w*2+1]; }
    outp[b*EN + e0]   = 0.5f*oA;
    outp[b*EN + e0+1] = 0.5f*oB;
  }
}

extern "C" void kernel_launch(void* const* d_in, const int* in_sizes, int n_in,
                              void* d_out, int out_size, void* d_ws, size_t ws_size,
                              hipStream_t stream)
{
  (void)in_sizes; (void)n_in; (void)out_size; (void)ws_size;
  const float* ecls = (const float*)d_in[0];
  const float* etok = (const float*)d_in[1];
  const float* mcls = (const float*)d_in[2];
  const float* mtok = (const float*)d_in[3];
  const float* maskp= (const float*)d_in[4];
  const float* Wq   = (const float*)d_in[5];
  const float* bq   = (const float*)d_in[6];
  const float* Wk   = (const float*)d_in[7];
  const float* bk   = (const float*)d_in[8];
  const float* Wv   = (const float*)d_in[9];
  const float* bv   = (const float*)d_in[10];
  const float* Wc   = (const float*)d_in[11];
  const float* bc   = (const float*)d_in[12];
  const float* lng  = (const float*)d_in[13];
  const float* lnb  = (const float*)d_in[14];

  char* ws = (char*)d_ws;
  size_t off = 0;
  auto take = [&](size_t bytes){ char* p = ws + off; off += (bytes + 255) & ~(size_t)255; return p; };
  ushort* a_ent = (ushort*)take((size_t)EN*PN*DIN*2);
  ushort* a_men = (ushort*)take((size_t)BN*PN*DIN*2);
  ushort* a_cls = (ushort*)take((size_t)EN*DIN*2);
  ushort* Wt    = (ushort*)take((size_t)4*HH*DIN*2);
  float*  bq_s  = (float*)take((size_t)HH*4);
  ushort* qo    = (ushort*)take((size_t)EN*PN*HH*2);
  ushort* ko    = (ushort*)take((size_t)BN*PN*HH*2);
  ushort* vo    = (ushort*)take((size_t)BN*PN*HH*2);
  float*  co    = (float*)take((size_t)EN*HH*4);

  prep_kernel<<<2048, 256, 0, stream>>>(etok, mtok, ecls, Wq, Wk, Wv, Wc, bq,
                                        a_ent, a_men, a_cls, Wt, bq_s);
  gemm_proj<<<dim3(200,4,1), 256, 0, stream>>>(a_ent, a_men, a_cls, Wt,
                                               bq_s, bk, bv, bc, qo, ko, vo, co);
  attn_kernel<<<1024, 512, 0, stream>>>(qo, ko, vo, co, maskp, mcls, ecls,
                                        lng, lnb, (float*)d_out);
}

// Round 5
// 554.940 us; speedup vs baseline: 1.0929x; 1.0043x over previous
//
#include <hip/hip_runtime.h>
#include <stdint.h>

#define EN 64
#define BN 32
#define PN 197
#define DIN 768
#define HH 512
#define RHO_ 4.0f

typedef __attribute__((ext_vector_type(8))) short bf16x8;
typedef __attribute__((ext_vector_type(4))) float f32x4;

__device__ __forceinline__ ushort f2bf(float f){
  unsigned u = __float_as_uint(f);
  u += 0x7FFFu + ((u >> 16) & 1u);
  return (ushort)(u >> 16);
}
__device__ __forceinline__ float bf2f(ushort h){ return __uint_as_float(((unsigned)h) << 16); }

// ---------------- prep: bf16 casts + scaled bias ----------------
__global__ __launch_bounds__(256) void prep_kernel(
    const float* __restrict__ etok, const float* __restrict__ mtok,
    const float* __restrict__ ecls, const float* __restrict__ bq,
    ushort* __restrict__ a_ent, ushort* __restrict__ a_men, ushort* __restrict__ a_cls,
    float* __restrict__ bq_s)
{
  int g = blockIdx.x*256 + threadIdx.x;
  int st = gridDim.x*256;
  const float s = 0.04419417382415922f; // 1/sqrt(512)
  for (int i=g; i<(EN*PN*DIN)/4; i+=st){
    float4 v = ((const float4*)etok)[i];
    ushort4 o; o.x=f2bf(v.x); o.y=f2bf(v.y); o.z=f2bf(v.z); o.w=f2bf(v.w);
    ((ushort4*)a_ent)[i] = o;
  }
  for (int i=g; i<(BN*PN*DIN)/4; i+=st){
    float4 v = ((const float4*)mtok)[i];
    ushort4 o; o.x=f2bf(v.x); o.y=f2bf(v.y); o.z=f2bf(v.z); o.w=f2bf(v.w);
    ((ushort4*)a_men)[i] = o;
  }
  for (int i=g; i<(EN*DIN)/4; i+=st){
    float4 v = ((const float4*)ecls)[i];
    ushort4 o; o.x=f2bf(v.x); o.y=f2bf(v.y); o.z=f2bf(v.z); o.w=f2bf(v.w);
    ((ushort4*)a_cls)[i] = o;
  }
  for (int i=g; i<HH; i+=st) bq_s[i] = bq[i]*s;
}

// ---------------- weight transpose via LDS tiles ----------------
// W [K=768][N=512] fp32 -> Wt [mat][N=512][K=768] bf16, coalesced both sides.
__global__ __launch_bounds__(256) void w_transpose(
    const float* __restrict__ Wq, const float* __restrict__ Wk,
    const float* __restrict__ Wv, const float* __restrict__ Wc,
    ushort* __restrict__ Wt)
{
  __shared__ float tl[64][65];
  int mat = blockIdx.z;
  const float* src = (mat==0)?Wq:(mat==1)?Wk:(mat==2)?Wv:Wc;
  float sc = (mat==0)? 0.04419417382415922f : 1.0f;
  int k0 = blockIdx.x*64;     // 12 tiles over K=768
  int n0 = blockIdx.y*64;     // 8 tiles over N=512
  int tid = threadIdx.x;
  int c = tid & 63, r0 = tid >> 6;
  #pragma unroll
  for (int i=0;i<16;++i){
    int r = r0 + i*4;
    tl[r][c] = src[(size_t)(k0+r)*HH + n0+c];   // consecutive c -> coalesced
  }
  __syncthreads();
  ushort* dst = Wt + (size_t)mat*HH*DIN;
  #pragma unroll
  for (int i=0;i<16;++i){
    int r = r0 + i*4;                            // r = n-row
    dst[(size_t)(n0+r)*DIN + k0+c] = f2bf(tl[c][r]*sc);  // consecutive c -> coalesced
  }
}

// ---------------- projection GEMMs: C = A @ Wt^T + bias ----------------
__global__ __launch_bounds__(256) void gemm_proj(
    const ushort* __restrict__ a_ent, const ushort* __restrict__ a_men, const ushort* __restrict__ a_cls,
    const ushort* __restrict__ Wt,
    const float* __restrict__ bq_s, const float* __restrict__ bk,
    const float* __restrict__ bv, const float* __restrict__ bc,
    ushort* __restrict__ qo, ushort* __restrict__ ko, ushort* __restrict__ vo,
    float* __restrict__ co)
{
  // compact block list: 99 tiles op0 (q), 50 op1 (k), 50 op2 (v), 1 op3 (cls)
  int x = blockIdx.x;
  int op, mt;
  if (x < 99)        { op = 0; mt = x; }
  else if (x < 149)  { op = 1; mt = x - 99; }
  else if (x < 199)  { op = 2; mt = x - 149; }
  else               { op = 3; mt = 0; }
  int M = (op==0)? EN*PN : (op==3)? EN : BN*PN;
  int m0 = mt*128;
  const ushort* A  = (op==0)? a_ent : (op==3)? a_cls : a_men;
  const ushort* Bw = Wt + (size_t)op*HH*DIN;
  const float* bias = (op==0)? bq_s : (op==1)? bk : (op==2)? bv : bc;
  int n0 = blockIdx.y*128;
  int Mm1 = M-1;

  __shared__ ushort As[128*40];
  __shared__ ushort Bs[128*40];
  int tid = threadIdx.x;
  int lane = tid & 63, wid = tid >> 6;
  int l15 = lane & 15, lg = lane >> 4;
  int wm = wid >> 1, wn = wid & 1;

  f32x4 acc[16];
  #pragma unroll
  for (int i=0;i<16;++i){ f32x4 z = {0.f,0.f,0.f,0.f}; acc[i] = z; }

  bf16x8 sA[2], sB[2];
  #pragma unroll
  for (int i=0;i<2;++i){
    int u = tid + i*256; int row = u>>2; int ko8 = (u&3)*8;
    int rA = m0+row; rA = rA>Mm1 ? Mm1 : rA;
    sA[i] = *(const bf16x8*)(A  + (size_t)rA*DIN + ko8);
    sB[i] = *(const bf16x8*)(Bw + (size_t)(n0+row)*DIN + ko8);
  }
  for (int kt=0; kt<DIN/32; ++kt){
    #pragma unroll
    for (int i=0;i<2;++i){
      int u = tid + i*256; int row = u>>2; int ko8 = (u&3)*8;
      *(bf16x8*)(&As[row*40 + ko8]) = sA[i];
      *(bf16x8*)(&Bs[row*40 + ko8]) = sB[i];
    }
    __syncthreads();
    if (kt < DIN/32 - 1){
      int k0 = (kt+1)*32;
      #pragma unroll
      for (int i=0;i<2;++i){
        int u = tid + i*256; int row = u>>2; int ko8 = (u&3)*8;
        int rA = m0+row; rA = rA>Mm1 ? Mm1 : rA;
        sA[i] = *(const bf16x8*)(A  + (size_t)rA*DIN + k0 + ko8);
        sB[i] = *(const bf16x8*)(Bw + (size_t)(n0+row)*DIN + k0 + ko8);
      }
    }
    bf16x8 af[4], bfg[4];
    #pragma unroll
    for (int t=0;t<4;++t){
      af[t]  = *(const bf16x8*)(&As[(wm*64 + t*16 + l15)*40 + lg*8]);
      bfg[t] = *(const bf16x8*)(&Bs[(wn*64 + t*16 + l15)*40 + lg*8]);
    }
    #pragma unroll
    for (int am=0; am<4; ++am)
      #pragma unroll
      for (int bn=0; bn<4; ++bn)
        acc[am*4+bn] = __builtin_amdgcn_mfma_f32_16x16x32_bf16(af[am], bfg[bn], acc[am*4+bn], 0, 0, 0);
    __syncthreads();
  }

  #pragma unroll
  for (int bn=0; bn<4; ++bn){
    int col = n0 + wn*64 + bn*16 + l15;
    float bval = bias[col];
    #pragma unroll
    for (int am=0; am<4; ++am){
      #pragma unroll
      for (int r=0;r<4;++r){
        int row = m0 + wm*64 + am*16 + lg*4 + r;
        if (row < M){
          float v = acc[am*4+bn][r] + bval;
          if (op==3)      co[(size_t)row*HH + col] = v;
          else if (op==0) qo[(size_t)row*HH + col] = f2bf(v);
          else if (op==1) ko[(size_t)row*HH + col] = f2bf(v);
          else            vo[(size_t)row*HH + col] = f2bf(v);
        }
      }
    }
  }
}

// ---------------- fused attention: 512 thr, dbuf 112-col chunks ----------------
// block = (b, e-pair); 8 waves, wave owns 16 q-rows, 2 row-passes (13 tiles).
// k staged per (kh, col-half) in double-buffered LDS; loads issued 1 chunk ahead.
// NOTE: no min-waves clamp — LDS caps at 1 block/CU; VGPR must stay <=256 (no spills).
__global__ __launch_bounds__(512) void attn_kernel(
    const ushort* __restrict__ qw, const ushort* __restrict__ kw, const ushort* __restrict__ vw,
    const float* __restrict__ cls_fc, const float* __restrict__ maskp,
    const float* __restrict__ mcls, const float* __restrict__ ecls,
    const float* __restrict__ lng, const float* __restrict__ lnb,
    float* __restrict__ outp)
{
  int bid = blockIdx.x;
  int b = bid >> 5;
  int e0 = (bid & 31) * 2;

  __shared__ ushort klds[2][112*256];   // [buf][local_col][k 256], 16B-unit XOR swizzle
  __shared__ float w_lds[2][208];
  __shared__ float red[32];

  int tid = threadIdx.x;
  int lane = tid & 63, wid = tid >> 6;
  int l15 = lane & 15, lg = (lane >> 4) & 3;

  for (int i=tid; i<416; i+=512) ((float*)w_lds)[i] = 0.f;

  const ushort* kb  = kw + (size_t)b*PN*HH;
  const ushort* qb0 = qw + (size_t)e0*PN*HH;
  const ushort* qb1 = qw + (size_t)(e0+1)*PN*HH;

  bf16x8 stg[7];
  bf16x8 afr[2][8];

  for (int rnd=0; rnd<2; ++rnd){
    int tt = rnd*8 + wid;
    bool active = tt < 13;
    int rt = active ? tt : 12;
    int arow = rt*16 + l15;
    int arowg = arow > 196 ? 196 : arow;

    f32x4 acc[2][13];
    #pragma unroll
    for (int e2=0;e2<2;++e2)
      #pragma unroll
      for (int i=0;i<13;++i){ f32x4 z={0.f,0.f,0.f,0.f}; acc[e2][i]=z; }

    // prologue: issue loads for chunk 0 (kh=0, col-half 0)
    #pragma unroll
    for (int i=0;i<7;++i){
      int u = tid + i*512; int col = u>>5, o32 = u&31;
      int cg = col > 196 ? 196 : col;
      stg[i] = *(const bf16x8*)(kb + (size_t)cg*HH + o32*8);
    }

    for (int c=0; c<4; ++c){
      int kh = c>>1, ch = c&1;
      __syncthreads();                       // prev compute done with buf[ch]
      #pragma unroll
      for (int i=0;i<7;++i){                 // stg -> buf[ch] (swizzled)
        int u = tid + i*512; int col = u>>5, o32 = u&31;
        *(bf16x8*)(&klds[ch][col*256 + ((o32 ^ (col&7))*8)]) = stg[i];
      }
      __syncthreads();                       // buf[ch] ready
      if (c < 3){                            // issue next chunk's loads (hidden under MFMA)
        int nkh = (c+1)>>1, ncb = ((c+1)&1)*112;
        #pragma unroll
        for (int i=0;i<7;++i){
          int u = tid + i*512; int col = u>>5, o32 = u&31;
          int cg = ncb + col; cg = cg > 196 ? 196 : cg;
          stg[i] = *(const bf16x8*)(kb + (size_t)cg*HH + nkh*256 + o32*8);
        }
      }
      if (ch == 0 && active){                // fresh kh: load q fragments
        #pragma unroll
        for (int lc=0; lc<8; ++lc){
          afr[0][lc] = *(const bf16x8*)(qb0 + (size_t)arowg*HH + kh*256 + lc*32 + lg*8);
          afr[1][lc] = *(const bf16x8*)(qb1 + (size_t)arowg*HH + kh*256 + lc*32 + lg*8);
        }
      }
      if (active){
        if (ch == 0){
          #pragma unroll
          for (int ct=0; ct<7; ++ct){
            int lcol = ct*16 + l15, sw = lcol & 7;
            #pragma unroll
            for (int lc=0; lc<8; ++lc){
              bf16x8 bfr = *(const bf16x8*)(&klds[0][lcol*256 + (((lc*4+lg) ^ sw)*8)]);
              acc[0][ct] = __builtin_amdgcn_mfma_f32_16x16x32_bf16(afr[0][lc], bfr, acc[0][ct], 0,0,0);
              acc[1][ct] = __builtin_amdgcn_mfma_f32_16x16x32_bf16(afr[1][lc], bfr, acc[1][ct], 0,0,0);
            }
          }
        } else {
          #pragma unroll
          for (int ct=0; ct<6; ++ct){        // tiles 7..12 (cols 112..207)
            int lcol = ct*16 + l15, sw = lcol & 7;
            #pragma unroll
            for (int lc=0; lc<8; ++lc){
              bf16x8 bfr = *(const bf16x8*)(&klds[1][lcol*256 + (((lc*4+lg) ^ sw)*8)]);
              acc[0][7+ct] = __builtin_amdgcn_mfma_f32_16x16x32_bf16(afr[0][lc], bfr, acc[0][7+ct], 0,0,0);
              acc[1][7+ct] = __builtin_amdgcn_mfma_f32_16x16x32_bf16(afr[1][lc], bfr, acc[1][7+ct], 0,0,0);
            }
          }
        }
      }
    }

    if (active){
      #pragma unroll
      for (int e2=0; e2<2; ++e2){
        if (l15 >= 5){                       // cols 197..207 invalid
          f32x4 ninf = {-1e30f,-1e30f,-1e30f,-1e30f};
          acc[e2][12] = ninf;
        }
        if (rt==0 && lg==0){                 // additive mask on query-row 0
          #pragma unroll
          for (int ct=0; ct<13; ++ct){
            int col = ct*16 + l15;
            if (col < 197) acc[e2][ct][0] += RHO_ * maskp[b*PN + col];
          }
        }
        float mrow[4], inv[4];
        #pragma unroll
        for (int r=0;r<4;++r){
          float m = acc[e2][0][r];
          #pragma unroll
          for (int ct=1; ct<13; ++ct) m = fmaxf(m, acc[e2][ct][r]);
          m = fmaxf(m, __shfl_xor(m,1));
          m = fmaxf(m, __shfl_xor(m,2));
          m = fmaxf(m, __shfl_xor(m,4));
          m = fmaxf(m, __shfl_xor(m,8));
          mrow[r] = m;
        }
        #pragma unroll
        for (int r=0;r<4;++r){
          float s = 0.f;
          #pragma unroll
          for (int ct=0; ct<13; ++ct){
            float ev = __expf(acc[e2][ct][r] - mrow[r]);
            acc[e2][ct][r] = ev;
            s += ev;
          }
          s += __shfl_xor(s,1); s += __shfl_xor(s,2);
          s += __shfl_xor(s,4); s += __shfl_xor(s,8);
          int prow = rt*16 + lg*4 + r;
          inv[r] = (prow < PN) ? 1.0f/s : 0.f;
        }
        #pragma unroll
        for (int ct=0; ct<13; ++ct){
          float cs = acc[e2][ct][0]*inv[0] + acc[e2][ct][1]*inv[1]
                   + acc[e2][ct][2]*inv[2] + acc[e2][ct][3]*inv[3];
          cs += __shfl_xor(cs,16);
          cs += __shfl_xor(cs,32);
          if (lg==0) atomicAdd(&w_lds[e2][ct*16 + l15], cs);
        }
      }
    }
  }
  __syncthreads();

  // phase 2: ctx[h] = (1/197) * sum_q w[q]*v[b,q,h]; thread owns h = tid
  const ushort* vb = vw + (size_t)b*PN*HH;
  float cA=0.f, cB=0.f;
  #pragma unroll 4
  for (int q=0; q<PN; ++q){
    float vq = bf2f(vb[(size_t)q*HH + tid]);
    cA += w_lds[0][q]*vq;
    cB += w_lds[1][q]*vq;
  }
  const float invP = 1.0f/197.0f;
  cA*=invP; cB*=invP;

  float sx = cA, sxx = cA*cA, sy = cB, syy = cB*cB;
  #pragma unroll
  for (int off=32; off; off>>=1){
    sx += __shfl_down(sx, off); sxx += __shfl_down(sxx, off);
    sy += __shfl_down(sy, off); syy += __shfl_down(syy, off);
  }
  if (lane==0){ red[wid*4+0]=sx; red[wid*4+1]=sxx; red[wid*4+2]=sy; red[wid*4+3]=syy; }
  __syncthreads();
  float s1A=0.f, s2A=0.f, s1B=0.f, s2B=0.f;
  #pragma unroll
  for (int w=0; w<8; ++w){
    s1A += red[w*4+0]; s2A += red[w*4+1];
    s1B += red[w*4+2]; s2B += red[w*4+3];
  }
  float muA = s1A*(1.f/512.f), muB = s1B*(1.f/512.f);
  float varA = s2A*(1.f/512.f) - muA*muA;
  float varB = s2B*(1.f/512.f) - muB*muB;
  float rsA = rsqrtf(varA + 1e-5f), rsB = rsqrtf(varB + 1e-5f);

  int h = tid;
  float g0=lng[h], bb0=lnb[h];
  float dA = ((cA-muA)*rsA*g0 + bb0) * cls_fc[(size_t)e0*HH + h];
  float dB = ((cB-muB)*rsB*g0 + bb0) * cls_fc[(size_t)(e0+1)*HH + h];

  // g2g: 768 dims over 512 threads (tid; tid+512 for tid<256)
  dA += mcls[b*DIN + tid]*ecls[(size_t)e0*DIN + tid];
  dB += mcls[b*DIN + tid]*ecls[(size_t)(e0+1)*DIN + tid];
  if (tid < 256){
    int j = tid + 512;
    dA += mcls[b*DIN + j]*ecls[(size_t)e0*DIN + j];
    dB += mcls[b*DIN + j]*ecls[(size_t)(e0+1)*DIN + j];
  }

  __syncthreads();
  #pragma unroll
  for (int off=32; off; off>>=1){ dA += __shfl_down(dA, off); dB += __shfl_down(dB, off); }
  if (lane==0){ red[wid*2+0]=dA; red[wid*2+1]=dB; }
  __syncthreads();
  if (tid==0){
    float oA=0.f, oB=0.f;
    #pragma unroll
    for (int w=0; w<8; ++w){ oA += red[w*2+0]; oB += red[w*2+1]; }
    outp[b*EN + e0]   = 0.5f*oA;
    outp[b*EN + e0+1] = 0.5f*oB;
  }
}

extern "C" void kernel_launch(void* const* d_in, const int* in_sizes, int n_in,
                              void* d_out, int out_size, void* d_ws, size_t ws_size,
                              hipStream_t stream)
{
  (void)in_sizes; (void)n_in; (void)out_size; (void)ws_size;
  const float* ecls = (const float*)d_in[0];
  const float* etok = (const float*)d_in[1];
  const float* mcls = (const float*)d_in[2];
  const float* mtok = (const float*)d_in[3];
  const float* maskp= (const float*)d_in[4];
  const float* Wq   = (const float*)d_in[5];
  const float* bq   = (const float*)d_in[6];
  const float* Wk   = (const float*)d_in[7];
  const float* bk   = (const float*)d_in[8];
  const float* Wv   = (const float*)d_in[9];
  const float* bv   = (const float*)d_in[10];
  const float* Wc   = (const float*)d_in[11];
  const float* bc   = (const float*)d_in[12];
  const float* lng  = (const float*)d_in[13];
  const float* lnb  = (const float*)d_in[14];

  char* ws = (char*)d_ws;
  size_t off = 0;
  auto take = [&](size_t bytes){ char* p = ws + off; off += (bytes + 255) & ~(size_t)255; return p; };
  ushort* a_ent = (ushort*)take((size_t)EN*PN*DIN*2);
  ushort* a_men = (ushort*)take((size_t)BN*PN*DIN*2);
  ushort* a_cls = (ushort*)take((size_t)EN*DIN*2);
  ushort* Wt    = (ushort*)take((size_t)4*HH*DIN*2);
  float*  bq_s  = (float*)take((size_t)HH*4);
  ushort* qo    = (ushort*)take((size_t)EN*PN*HH*2);
  ushort* ko    = (ushort*)take((size_t)BN*PN*HH*2);
  ushort* vo    = (ushort*)take((size_t)BN*PN*HH*2);
  float*  co    = (float*)take((size_t)EN*HH*4);

  prep_kernel<<<1024, 256, 0, stream>>>(etok, mtok, ecls, bq, a_ent, a_men, a_cls, bq_s);
  w_transpose<<<dim3(12,8,4), 256, 0, stream>>>(Wq, Wk, Wv, Wc, Wt);
  gemm_proj<<<dim3(200,4,1), 256, 0, stream>>>(a_ent, a_men, a_cls, Wt,
                                               bq_s, bk, bv, bc, qo, ko, vo, co);
  attn_kernel<<<1024, 512, 0, stream>>>(qo, ko, vo, co, maskp, mcls, ecls,
                                        lng, lnb, (float*)d_out);
}

// Round 6
// 481.867 us; speedup vs baseline: 1.2587x; 1.1516x over previous
//
#include <hip/hip_runtime.h>
#include <stdint.h>

#define EN 64
#define BN 32
#define PN 197
#define DIN 768
#define HH 512
#define RHO_ 4.0f

typedef __attribute__((ext_vector_type(8))) short bf16x8;
typedef __attribute__((ext_vector_type(4))) float f32x4;

__device__ __forceinline__ ushort f2bf(float f){
  unsigned u = __float_as_uint(f);
  u += 0x7FFFu + ((u >> 16) & 1u);
  return (ushort)(u >> 16);
}
__device__ __forceinline__ float bf2f(ushort h){ return __uint_as_float(((unsigned)h) << 16); }

// async global->LDS, 16B per lane; LDS dest = wave-uniform base + lane*16
#define GLOAD_LDS16(g, l) __builtin_amdgcn_global_load_lds( \
    (const __attribute__((address_space(1))) void*)(g), \
    (__attribute__((address_space(3))) void*)(l), 16, 0, 0)

// ---------------- prep: bf16 casts + scaled bias ----------------
__global__ __launch_bounds__(256) void prep_kernel(
    const float* __restrict__ etok, const float* __restrict__ mtok,
    const float* __restrict__ ecls, const float* __restrict__ bq,
    ushort* __restrict__ a_ent, ushort* __restrict__ a_men, ushort* __restrict__ a_cls,
    float* __restrict__ bq_s)
{
  int g = blockIdx.x*256 + threadIdx.x;
  int st = gridDim.x*256;
  const float s = 0.04419417382415922f; // 1/sqrt(512)
  for (int i=g; i<(EN*PN*DIN)/4; i+=st){
    float4 v = ((const float4*)etok)[i];
    ushort4 o; o.x=f2bf(v.x); o.y=f2bf(v.y); o.z=f2bf(v.z); o.w=f2bf(v.w);
    ((ushort4*)a_ent)[i] = o;
  }
  for (int i=g; i<(BN*PN*DIN)/4; i+=st){
    float4 v = ((const float4*)mtok)[i];
    ushort4 o; o.x=f2bf(v.x); o.y=f2bf(v.y); o.z=f2bf(v.z); o.w=f2bf(v.w);
    ((ushort4*)a_men)[i] = o;
  }
  for (int i=g; i<(EN*DIN)/4; i+=st){
    float4 v = ((const float4*)ecls)[i];
    ushort4 o; o.x=f2bf(v.x); o.y=f2bf(v.y); o.z=f2bf(v.z); o.w=f2bf(v.w);
    ((ushort4*)a_cls)[i] = o;
  }
  for (int i=g; i<HH; i+=st) bq_s[i] = bq[i]*s;
}

// ---------------- weight transpose via LDS tiles ----------------
__global__ __launch_bounds__(256) void w_transpose(
    const float* __restrict__ Wq, const float* __restrict__ Wk,
    const float* __restrict__ Wv, const float* __restrict__ Wc,
    ushort* __restrict__ Wt)
{
  __shared__ float tl[64][65];
  int mat = blockIdx.z;
  const float* src = (mat==0)?Wq:(mat==1)?Wk:(mat==2)?Wv:Wc;
  float sc = (mat==0)? 0.04419417382415922f : 1.0f;
  int k0 = blockIdx.x*64;
  int n0 = blockIdx.y*64;
  int tid = threadIdx.x;
  int c = tid & 63, r0 = tid >> 6;
  #pragma unroll
  for (int i=0;i<16;++i){
    int r = r0 + i*4;
    tl[r][c] = src[(size_t)(k0+r)*HH + n0+c];
  }
  __syncthreads();
  ushort* dst = Wt + (size_t)mat*HH*DIN;
  #pragma unroll
  for (int i=0;i<16;++i){
    int r = r0 + i*4;
    dst[(size_t)(n0+r)*DIN + k0+c] = f2bf(tl[c][r]*sc);
  }
}

// ---------------- projection GEMMs: C = A @ Wt^T + bias ----------------
__global__ __launch_bounds__(256) void gemm_proj(
    const ushort* __restrict__ a_ent, const ushort* __restrict__ a_men, const ushort* __restrict__ a_cls,
    const ushort* __restrict__ Wt,
    const float* __restrict__ bq_s, const float* __restrict__ bk,
    const float* __restrict__ bv, const float* __restrict__ bc,
    ushort* __restrict__ qo, ushort* __restrict__ ko, ushort* __restrict__ vo,
    float* __restrict__ co)
{
  int x = blockIdx.x;
  int op, mt;
  if (x < 99)        { op = 0; mt = x; }
  else if (x < 149)  { op = 1; mt = x - 99; }
  else if (x < 199)  { op = 2; mt = x - 149; }
  else               { op = 3; mt = 0; }
  int M = (op==0)? EN*PN : (op==3)? EN : BN*PN;
  int m0 = mt*128;
  const ushort* A  = (op==0)? a_ent : (op==3)? a_cls : a_men;
  const ushort* Bw = Wt + (size_t)op*HH*DIN;
  const float* bias = (op==0)? bq_s : (op==1)? bk : (op==2)? bv : bc;
  int n0 = blockIdx.y*128;
  int Mm1 = M-1;

  __shared__ ushort As[128*40];
  __shared__ ushort Bs[128*40];
  int tid = threadIdx.x;
  int lane = tid & 63, wid = tid >> 6;
  int l15 = lane & 15, lg = lane >> 4;
  int wm = wid >> 1, wn = wid & 1;

  f32x4 acc[16];
  #pragma unroll
  for (int i=0;i<16;++i){ f32x4 z = {0.f,0.f,0.f,0.f}; acc[i] = z; }

  bf16x8 sA[2], sB[2];
  #pragma unroll
  for (int i=0;i<2;++i){
    int u = tid + i*256; int row = u>>2; int ko8 = (u&3)*8;
    int rA = m0+row; rA = rA>Mm1 ? Mm1 : rA;
    sA[i] = *(const bf16x8*)(A  + (size_t)rA*DIN + ko8);
    sB[i] = *(const bf16x8*)(Bw + (size_t)(n0+row)*DIN + ko8);
  }
  for (int kt=0; kt<DIN/32; ++kt){
    #pragma unroll
    for (int i=0;i<2;++i){
      int u = tid + i*256; int row = u>>2; int ko8 = (u&3)*8;
      *(bf16x8*)(&As[row*40 + ko8]) = sA[i];
      *(bf16x8*)(&Bs[row*40 + ko8]) = sB[i];
    }
    __syncthreads();
    if (kt < DIN/32 - 1){
      int k0 = (kt+1)*32;
      #pragma unroll
      for (int i=0;i<2;++i){
        int u = tid + i*256; int row = u>>2; int ko8 = (u&3)*8;
        int rA = m0+row; rA = rA>Mm1 ? Mm1 : rA;
        sA[i] = *(const bf16x8*)(A  + (size_t)rA*DIN + k0 + ko8);
        sB[i] = *(const bf16x8*)(Bw + (size_t)(n0+row)*DIN + k0 + ko8);
      }
    }
    bf16x8 af[4], bfg[4];
    #pragma unroll
    for (int t=0;t<4;++t){
      af[t]  = *(const bf16x8*)(&As[(wm*64 + t*16 + l15)*40 + lg*8]);
      bfg[t] = *(const bf16x8*)(&Bs[(wn*64 + t*16 + l15)*40 + lg*8]);
    }
    #pragma unroll
    for (int am=0; am<4; ++am)
      #pragma unroll
      for (int bn=0; bn<4; ++bn)
        acc[am*4+bn] = __builtin_amdgcn_mfma_f32_16x16x32_bf16(af[am], bfg[bn], acc[am*4+bn], 0, 0, 0);
    __syncthreads();
  }

  #pragma unroll
  for (int bn=0; bn<4; ++bn){
    int col = n0 + wn*64 + bn*16 + l15;
    float bval = bias[col];
    #pragma unroll
    for (int am=0; am<4; ++am){
      #pragma unroll
      for (int r=0;r<4;++r){
        int row = m0 + wm*64 + am*16 + lg*4 + r;
        if (row < M){
          float v = acc[am*4+bn][r] + bval;
          if (op==3)      co[(size_t)row*HH + col] = v;
          else if (op==0) qo[(size_t)row*HH + col] = f2bf(v);
          else if (op==1) ko[(size_t)row*HH + col] = f2bf(v);
          else            vo[(size_t)row*HH + col] = f2bf(v);
        }
      }
    }
  }
}

// ---------------- fused attention: gload_lds staging, low-VGPR ----------------
// block=(b,e-pair); 8 waves; wave owns 16 q-rows per pass, 2 passes (13 tiles).
// k staged via global_load_lds (linear LDS dest, source-side XOR swizzle);
// q fragments pipelined per k-slice (1-deep) to keep VGPR < 256 (no spills).
__global__ __launch_bounds__(512) void attn_kernel(
    const ushort* __restrict__ qw, const ushort* __restrict__ kw, const ushort* __restrict__ vw,
    const float* __restrict__ cls_fc, const float* __restrict__ maskp,
    const float* __restrict__ mcls, const float* __restrict__ ecls,
    const float* __restrict__ lng, const float* __restrict__ lnb,
    float* __restrict__ outp)
{
  int bid = blockIdx.x;
  int b = bid >> 5;
  int e0 = (bid & 31) * 2;

  __shared__ ushort klds[2][112*256];   // [buf][col][k256]; unit (col,j) holds global (col, j^(col&7))
  __shared__ float w_lds[2][208];
  __shared__ float red[32];

  int tid = threadIdx.x;
  int lane = tid & 63, wid = tid >> 6;
  int l15 = lane & 15, lg = (lane >> 4) & 3;

  for (int i=tid; i<416; i+=512) ((float*)w_lds)[i] = 0.f;

  const ushort* kb  = kw + (size_t)b*PN*HH;
  const ushort* qb0 = qw + (size_t)e0*PN*HH;
  const ushort* qb1 = qw + (size_t)(e0+1)*PN*HH;

  // stage one 112-col x 256-k chunk into klds[ch] via global_load_lds.
  // lane unit L = tid + i*512 ; LDS linear ; global source column-swizzled.
  auto issue = [&](int ch, int kh, int cb){
    #pragma unroll
    for (int i=0;i<7;++i){
      int L   = tid + i*512;
      int col = L >> 5, j = L & 31;
      int cg  = cb + col; cg = cg > 196 ? 196 : cg;
      const ushort* src = kb + (size_t)cg*HH + kh*256 + ((j ^ (col & 7)) * 8);
      ushort* dst = &klds[ch][ (size_t)(wid*64 + i*512) * 8 ];   // wave-uniform
      GLOAD_LDS16(src, dst);
    }
  };

  for (int rnd=0; rnd<2; ++rnd){
    int tt = rnd*8 + wid;
    bool active = tt < 13;
    int rt = active ? tt : 12;
    int arow = rt*16 + l15;
    int arowg = arow > 196 ? 196 : arow;

    f32x4 acc[2][13];
    #pragma unroll
    for (int e2=0;e2<2;++e2)
      #pragma unroll
      for (int i=0;i<13;++i){ f32x4 z={0.f,0.f,0.f,0.f}; acc[e2][i]=z; }

    const ushort* q0base = qb0 + (size_t)arowg*HH + lg*8;
    const ushort* q1base = qb1 + (size_t)arowg*HH + lg*8;

    if (rnd==0) issue(0, 0, 0);          // chunk 0 -> buf0

    for (int c=0; c<4; ++c){
      int kh = c>>1, ch = c&1;
      __syncthreads();                   // drains vmcnt(0): chunk c landed; prev compute done
      if (c < 3)            issue(ch^1, (c+1)>>1, ((c+1)&1)*112);
      else if (rnd == 0)    issue(0, 0, 0);   // prefetch rnd1 chunk0 under softmax
      if (active){
        const ushort* q0 = q0base + kh*256;
        const ushort* q1 = q1base + kh*256;
        bf16x8 a0 = *(const bf16x8*)q0;
        bf16x8 a1 = *(const bf16x8*)q1;
        if (ch == 0){
          #pragma unroll 1
          for (int lc=0; lc<8; ++lc){
            bf16x8 c0 = a0, c1 = a1;
            int nx = (lc<7 ? lc+1 : lc)*32;
            a0 = *(const bf16x8*)(q0 + nx);
            a1 = *(const bf16x8*)(q1 + nx);
            int ru = lc*4 + lg;
            #pragma unroll
            for (int ct=0; ct<7; ++ct){
              int lcol = ct*16 + l15;
              bf16x8 bfr = *(const bf16x8*)(&klds[0][lcol*256 + ((ru ^ (lcol&7))*8)]);
              acc[0][ct] = __builtin_amdgcn_mfma_f32_16x16x32_bf16(c0, bfr, acc[0][ct], 0,0,0);
              acc[1][ct] = __builtin_amdgcn_mfma_f32_16x16x32_bf16(c1, bfr, acc[1][ct], 0,0,0);
            }
          }
        } else {
          #pragma unroll 1
          for (int lc=0; lc<8; ++lc){
            bf16x8 c0 = a0, c1 = a1;
            int nx = (lc<7 ? lc+1 : lc)*32;
            a0 = *(const bf16x8*)(q0 + nx);
            a1 = *(const bf16x8*)(q1 + nx);
            int ru = lc*4 + lg;
            #pragma unroll
            for (int ct=0; ct<6; ++ct){
              int lcol = ct*16 + l15;
              bf16x8 bfr = *(const bf16x8*)(&klds[1][lcol*256 + ((ru ^ (lcol&7))*8)]);
              acc[0][7+ct] = __builtin_amdgcn_mfma_f32_16x16x32_bf16(c0, bfr, acc[0][7+ct], 0,0,0);
              acc[1][7+ct] = __builtin_amdgcn_mfma_f32_16x16x32_bf16(c1, bfr, acc[1][7+ct], 0,0,0);
            }
          }
        }
      }
    }

    if (active){
      #pragma unroll
      for (int e2=0; e2<2; ++e2){
        if (l15 >= 5){                       // cols 197..207 invalid
          f32x4 ninf = {-1e30f,-1e30f,-1e30f,-1e30f};
          acc[e2][12] = ninf;
        }
        if (rt==0 && lg==0){                 // additive mask on query-row 0
          #pragma unroll
          for (int ct=0; ct<13; ++ct){
            int col = ct*16 + l15;
            if (col < 197) acc[e2][ct][0] += RHO_ * maskp[b*PN + col];
          }
        }
        float mrow[4], inv[4];
        #pragma unroll
        for (int r=0;r<4;++r){
          float m = acc[e2][0][r];
          #pragma unroll
          for (int ct=1; ct<13; ++ct) m = fmaxf(m, acc[e2][ct][r]);
          m = fmaxf(m, __shfl_xor(m,1));
          m = fmaxf(m, __shfl_xor(m,2));
          m = fmaxf(m, __shfl_xor(m,4));
          m = fmaxf(m, __shfl_xor(m,8));
          mrow[r] = m;
        }
        #pragma unroll
        for (int r=0;r<4;++r){
          float s = 0.f;
          #pragma unroll
          for (int ct=0; ct<13; ++ct){
            float ev = __expf(acc[e2][ct][r] - mrow[r]);
            acc[e2][ct][r] = ev;
            s += ev;
          }
          s += __shfl_xor(s,1); s += __shfl_xor(s,2);
          s += __shfl_xor(s,4); s += __shfl_xor(s,8);
          int prow = rt*16 + lg*4 + r;
          inv[r] = (prow < PN) ? 1.0f/s : 0.f;
        }
        #pragma unroll
        for (int ct=0; ct<13; ++ct){
          float cs = acc[e2][ct][0]*inv[0] + acc[e2][ct][1]*inv[1]
                   + acc[e2][ct][2]*inv[2] + acc[e2][ct][3]*inv[3];
          cs += __shfl_xor(cs,16);
          cs += __shfl_xor(cs,32);
          if (lg==0) atomicAdd(&w_lds[e2][ct*16 + l15], cs);
        }
      }
    }
  }
  __syncthreads();

  // phase 2: ctx[h] = (1/197) * sum_q w[q]*v[b,q,h]; thread owns h = tid
  const ushort* vb = vw + (size_t)b*PN*HH;
  float cA=0.f, cB=0.f;
  #pragma unroll 4
  for (int q=0; q<PN; ++q){
    float vq = bf2f(vb[(size_t)q*HH + tid]);
    cA += w_lds[0][q]*vq;
    cB += w_lds[1][q]*vq;
  }
  const float invP = 1.0f/197.0f;
  cA*=invP; cB*=invP;

  float sx = cA, sxx = cA*cA, sy = cB, syy = cB*cB;
  #pragma unroll
  for (int off=32; off; off>>=1){
    sx += __shfl_down(sx, off); sxx += __shfl_down(sxx, off);
    sy += __shfl_down(sy, off); syy += __shfl_down(syy, off);
  }
  if (lane==0){ red[wid*4+0]=sx; red[wid*4+1]=sxx; red[wid*4+2]=sy; red[wid*4+3]=syy; }
  __syncthreads();
  float s1A=0.f, s2A=0.f, s1B=0.f, s2B=0.f;
  #pragma unroll
  for (int w=0; w<8; ++w){
    s1A += red[w*4+0]; s2A += red[w*4+1];
    s1B += red[w*4+2]; s2B += red[w*4+3];
  }
  float muA = s1A*(1.f/512.f), muB = s1B*(1.f/512.f);
  float varA = s2A*(1.f/512.f) - muA*muA;
  float varB = s2B*(1.f/512.f) - muB*muB;
  float rsA = rsqrtf(varA + 1e-5f), rsB = rsqrtf(varB + 1e-5f);

  int h = tid;
  float g0=lng[h], bb0=lnb[h];
  float dA = ((cA-muA)*rsA*g0 + bb0) * cls_fc[(size_t)e0*HH + h];
  float dB = ((cB-muB)*rsB*g0 + bb0) * cls_fc[(size_t)(e0+1)*HH + h];

  // g2g: 768 dims over 512 threads
  dA += mcls[b*DIN + tid]*ecls[(size_t)e0*DIN + tid];
  dB += mcls[b*DIN + tid]*ecls[(size_t)(e0+1)*DIN + tid];
  if (tid < 256){
    int j = tid + 512;
    dA += mcls[b*DIN + j]*ecls[(size_t)e0*DIN + j];
    dB += mcls[b*DIN + j]*ecls[(size_t)(e0+1)*DIN + j];
  }

  __syncthreads();
  #pragma unroll
  for (int off=32; off; off>>=1){ dA += __shfl_down(dA, off); dB += __shfl_down(dB, off); }
  if (lane==0){ red[wid*2+0]=dA; red[wid*2+1]=dB; }
  __syncthreads();
  if (tid==0){
    float oA=0.f, oB=0.f;
    #pragma unroll
    for (int w=0; w<8; ++w){ oA += red[w*2+0]; oB += red[w*2+1]; }
    outp[b*EN + e0]   = 0.5f*oA;
    outp[b*EN + e0+1] = 0.5f*oB;
  }
}

extern "C" void kernel_launch(void* const* d_in, const int* in_sizes, int n_in,
                              void* d_out, int out_size, void* d_ws, size_t ws_size,
                              hipStream_t stream)
{
  (void)in_sizes; (void)n_in; (void)out_size; (void)ws_size;
  const float* ecls = (const float*)d_in[0];
  const float* etok = (const float*)d_in[1];
  const float* mcls = (const float*)d_in[2];
  const float* mtok = (const float*)d_in[3];
  const float* maskp= (const float*)d_in[4];
  const float* Wq   = (const float*)d_in[5];
  const float* bq   = (const float*)d_in[6];
  const float* Wk   = (const float*)d_in[7];
  const float* bk   = (const float*)d_in[8];
  const float* Wv   = (const float*)d_in[9];
  const float* bv   = (const float*)d_in[10];
  const float* Wc   = (const float*)d_in[11];
  const float* bc   = (const float*)d_in[12];
  const float* lng  = (const float*)d_in[13];
  const float* lnb  = (const float*)d_in[14];

  char* ws = (char*)d_ws;
  size_t off = 0;
  auto take = [&](size_t bytes){ char* p = ws + off; off += (bytes + 255) & ~(size_t)255; return p; };
  ushort* a_ent = (ushort*)take((size_t)EN*PN*DIN*2);
  ushort* a_men = (ushort*)take((size_t)BN*PN*DIN*2);
  ushort* a_cls = (ushort*)take((size_t)EN*DIN*2);
  ushort* Wt    = (ushort*)take((size_t)4*HH*DIN*2);
  float*  bq_s  = (float*)take((size_t)HH*4);
  ushort* qo    = (ushort*)take((size_t)EN*PN*HH*2);
  ushort* ko    = (ushort*)take((size_t)BN*PN*HH*2);
  ushort* vo    = (ushort*)take((size_t)BN*PN*HH*2);
  float*  co    = (float*)take((size_t)EN*HH*4);

  prep_kernel<<<1024, 256, 0, stream>>>(etok, mtok, ecls, bq, a_ent, a_men, a_cls, bq_s);
  w_transpose<<<dim3(12,8,4), 256, 0, stream>>>(Wq, Wk, Wv, Wc, Wt);
  gemm_proj<<<dim3(200,4,1), 256, 0, stream>>>(a_ent, a_men, a_cls, Wt,
                                               bq_s, bk, bv, bc, qo, ko, vo, co);
  attn_kernel<<<1024, 512, 0, stream>>>(qo, ko, vo, co, maskp, mcls, ecls,
                                        lng, lnb, (float*)d_out);
}

// Round 7
// 472.935 us; speedup vs baseline: 1.2824x; 1.0189x over previous
//
#include <hip/hip_runtime.h>
#include <stdint.h>

#define EN 64
#define BN 32
#define PN 197
#define DIN 768
#define HH 512
#define RHO_ 4.0f

typedef __attribute__((ext_vector_type(8))) short bf16x8;
typedef __attribute__((ext_vector_type(4))) float f32x4;

__device__ __forceinline__ ushort f2bf(float f){
  unsigned u = __float_as_uint(f);
  u += 0x7FFFu + ((u >> 16) & 1u);
  return (ushort)(u >> 16);
}
__device__ __forceinline__ float bf2f(ushort h){ return __uint_as_float(((unsigned)h) << 16); }

// async global->LDS, 16B per lane; LDS dest = wave-uniform base + lane*16
#define GLOAD_LDS16(g, l) __builtin_amdgcn_global_load_lds( \
    (const __attribute__((address_space(1))) void*)(g), \
    (__attribute__((address_space(3))) void*)(l), 16, 0, 0)

// ---------------- prep: bf16 casts + scaled bias ----------------
__global__ __launch_bounds__(256) void prep_kernel(
    const float* __restrict__ etok, const float* __restrict__ mtok,
    const float* __restrict__ ecls, const float* __restrict__ bq,
    ushort* __restrict__ a_ent, ushort* __restrict__ a_men, ushort* __restrict__ a_cls,
    float* __restrict__ bq_s)
{
  int g = blockIdx.x*256 + threadIdx.x;
  int st = gridDim.x*256;
  const float s = 0.04419417382415922f; // 1/sqrt(512)
  for (int i=g; i<(EN*PN*DIN)/4; i+=st){
    float4 v = ((const float4*)etok)[i];
    ushort4 o; o.x=f2bf(v.x); o.y=f2bf(v.y); o.z=f2bf(v.z); o.w=f2bf(v.w);
    ((ushort4*)a_ent)[i] = o;
  }
  for (int i=g; i<(BN*PN*DIN)/4; i+=st){
    float4 v = ((const float4*)mtok)[i];
    ushort4 o; o.x=f2bf(v.x); o.y=f2bf(v.y); o.z=f2bf(v.z); o.w=f2bf(v.w);
    ((ushort4*)a_men)[i] = o;
  }
  for (int i=g; i<(EN*DIN)/4; i+=st){
    float4 v = ((const float4*)ecls)[i];
    ushort4 o; o.x=f2bf(v.x); o.y=f2bf(v.y); o.z=f2bf(v.z); o.w=f2bf(v.w);
    ((ushort4*)a_cls)[i] = o;
  }
  for (int i=g; i<HH; i+=st) bq_s[i] = bq[i]*s;
}

// ---------------- weight transpose via LDS tiles ----------------
__global__ __launch_bounds__(256) void w_transpose(
    const float* __restrict__ Wq, const float* __restrict__ Wk,
    const float* __restrict__ Wv, const float* __restrict__ Wc,
    ushort* __restrict__ Wt)
{
  __shared__ float tl[64][65];
  int mat = blockIdx.z;
  const float* src = (mat==0)?Wq:(mat==1)?Wk:(mat==2)?Wv:Wc;
  float sc = (mat==0)? 0.04419417382415922f : 1.0f;
  int k0 = blockIdx.x*64;
  int n0 = blockIdx.y*64;
  int tid = threadIdx.x;
  int c = tid & 63, r0 = tid >> 6;
  #pragma unroll
  for (int i=0;i<16;++i){
    int r = r0 + i*4;
    tl[r][c] = src[(size_t)(k0+r)*HH + n0+c];
  }
  __syncthreads();
  ushort* dst = Wt + (size_t)mat*HH*DIN;
  #pragma unroll
  for (int i=0;i<16;++i){
    int r = r0 + i*4;
    dst[(size_t)(n0+r)*DIN + k0+c] = f2bf(tl[c][r]*sc);
  }
}

// ---------------- projection GEMMs: C = A @ Wt^T + bias ----------------
__global__ __launch_bounds__(256) void gemm_proj(
    const ushort* __restrict__ a_ent, const ushort* __restrict__ a_men, const ushort* __restrict__ a_cls,
    const ushort* __restrict__ Wt,
    const float* __restrict__ bq_s, const float* __restrict__ bk,
    const float* __restrict__ bv, const float* __restrict__ bc,
    ushort* __restrict__ qo, ushort* __restrict__ ko, ushort* __restrict__ vo,
    float* __restrict__ co)
{
  int x = blockIdx.x;
  int op, mt;
  if (x < 99)        { op = 0; mt = x; }
  else if (x < 149)  { op = 1; mt = x - 99; }
  else if (x < 199)  { op = 2; mt = x - 149; }
  else               { op = 3; mt = 0; }
  int M = (op==0)? EN*PN : (op==3)? EN : BN*PN;
  int m0 = mt*128;
  const ushort* A  = (op==0)? a_ent : (op==3)? a_cls : a_men;
  const ushort* Bw = Wt + (size_t)op*HH*DIN;
  const float* bias = (op==0)? bq_s : (op==1)? bk : (op==2)? bv : bc;
  int n0 = blockIdx.y*128;
  int Mm1 = M-1;

  __shared__ ushort As[128*40];
  __shared__ ushort Bs[128*40];
  int tid = threadIdx.x;
  int lane = tid & 63, wid = tid >> 6;
  int l15 = lane & 15, lg = lane >> 4;
  int wm = wid >> 1, wn = wid & 1;

  f32x4 acc[16];
  #pragma unroll
  for (int i=0;i<16;++i){ f32x4 z = {0.f,0.f,0.f,0.f}; acc[i] = z; }

  bf16x8 sA[2], sB[2];
  #pragma unroll
  for (int i=0;i<2;++i){
    int u = tid + i*256; int row = u>>2; int ko8 = (u&3)*8;
    int rA = m0+row; rA = rA>Mm1 ? Mm1 : rA;
    sA[i] = *(const bf16x8*)(A  + (size_t)rA*DIN + ko8);
    sB[i] = *(const bf16x8*)(Bw + (size_t)(n0+row)*DIN + ko8);
  }
  for (int kt=0; kt<DIN/32; ++kt){
    #pragma unroll
    for (int i=0;i<2;++i){
      int u = tid + i*256; int row = u>>2; int ko8 = (u&3)*8;
      *(bf16x8*)(&As[row*40 + ko8]) = sA[i];
      *(bf16x8*)(&Bs[row*40 + ko8]) = sB[i];
    }
    __syncthreads();
    if (kt < DIN/32 - 1){
      int k0 = (kt+1)*32;
      #pragma unroll
      for (int i=0;i<2;++i){
        int u = tid + i*256; int row = u>>2; int ko8 = (u&3)*8;
        int rA = m0+row; rA = rA>Mm1 ? Mm1 : rA;
        sA[i] = *(const bf16x8*)(A  + (size_t)rA*DIN + k0 + ko8);
        sB[i] = *(const bf16x8*)(Bw + (size_t)(n0+row)*DIN + k0 + ko8);
      }
    }
    bf16x8 af[4], bfg[4];
    #pragma unroll
    for (int t=0;t<4;++t){
      af[t]  = *(const bf16x8*)(&As[(wm*64 + t*16 + l15)*40 + lg*8]);
      bfg[t] = *(const bf16x8*)(&Bs[(wn*64 + t*16 + l15)*40 + lg*8]);
    }
    #pragma unroll
    for (int am=0; am<4; ++am)
      #pragma unroll
      for (int bn=0; bn<4; ++bn)
        acc[am*4+bn] = __builtin_amdgcn_mfma_f32_16x16x32_bf16(af[am], bfg[bn], acc[am*4+bn], 0, 0, 0);
    __syncthreads();
  }

  #pragma unroll
  for (int bn=0; bn<4; ++bn){
    int col = n0 + wn*64 + bn*16 + l15;
    float bval = bias[col];
    #pragma unroll
    for (int am=0; am<4; ++am){
      #pragma unroll
      for (int r=0;r<4;++r){
        int row = m0 + wm*64 + am*16 + lg*4 + r;
        if (row < M){
          float v = acc[am*4+bn][r] + bval;
          if (op==3)      co[(size_t)row*HH + col] = v;
          else if (op==0) qo[(size_t)row*HH + col] = f2bf(v);
          else if (op==1) ko[(size_t)row*HH + col] = f2bf(v);
          else            vo[(size_t)row*HH + col] = f2bf(v);
        }
      }
    }
  }
}

// ---------------- fused attention: k-chunk staging (208 cols x 64 k) ----------------
// block=(b,e-pair), 512 thr, 8 waves. Flat g-loop: 16 chunks = 2 row-passes x 8 k-chunks.
// k chunk staged via global_load_lds (source-side XOR swizzle, linear LDS dest).
// q loaded once per chunk (4 x 16B), prefetched one full chunk ahead.
__global__ __launch_bounds__(512) void attn_kernel(
    const ushort* __restrict__ qw, const ushort* __restrict__ kw, const ushort* __restrict__ vw,
    const float* __restrict__ cls_fc, const float* __restrict__ maskp,
    const float* __restrict__ mcls, const float* __restrict__ ecls,
    const float* __restrict__ lng, const float* __restrict__ lnb,
    float* __restrict__ outp)
{
  int bid = blockIdx.x;
  int b = bid >> 5;
  int e0 = (bid & 31) * 2;

  __shared__ ushort klds[2][1664*8];   // [buf][unit(col*8+j)*8]; 16B units, 208 cols x 64 k
  __shared__ float w_lds[2][208];
  __shared__ float red[32];

  int tid = threadIdx.x;
  int lane = tid & 63, wid = tid >> 6;
  int l15 = lane & 15, lg = (lane >> 4) & 3;

  for (int i=tid; i<416; i+=512) ((float*)w_lds)[i] = 0.f;

  const ushort* kb = kw + (size_t)b*PN*HH;
  const ushort* qb0 = qw + (size_t)e0*PN*HH;
  const ushort* qb1 = qw + (size_t)(e0+1)*PN*HH;

  // stage chunk kc (k-range kc*64..+64, all 208 cols) into klds[bf].
  // unit (col, j) holds global k[col][kc*64 + (j^(col&7))*8 ..+8]
  auto issue = [&](int bf, int kc){
    #pragma unroll
    for (int i=0;i<4;++i){
      int L = tid + i*512;
      if (L < 1664){
        int col = L >> 3, j = L & 7;
        int cg = col > 196 ? 196 : col;
        const ushort* src = kb + (size_t)cg*HH + kc*64 + ((j ^ (col & 7)) * 8);
        ushort* dst = &klds[bf][ (wid*64 + i*512) * 8 ];   // wave-uniform base
        GLOAD_LDS16(src, dst);
      }
    }
  };

  // q row base pointers for both passes (rnd 0: tiles 0..7; rnd 1: tiles 8..12)
  int ar0 = wid*16 + l15;                 // <= 127, valid
  int tt1 = 8 + wid;
  int rt1 = tt1 > 12 ? 12 : tt1;
  int ar1 = rt1*16 + l15; ar1 = ar1 > 196 ? 196 : ar1;
  const ushort* q00 = qb0 + (size_t)ar0*HH + lg*8;
  const ushort* q01 = qb1 + (size_t)ar0*HH + lg*8;
  const ushort* q10 = qb0 + (size_t)ar1*HH + lg*8;
  const ushort* q11 = qb1 + (size_t)ar1*HH + lg*8;

  f32x4 acc[2][13];
  #pragma unroll
  for (int e2=0;e2<2;++e2)
    #pragma unroll
    for (int i=0;i<13;++i){ f32x4 z={0.f,0.f,0.f,0.f}; acc[e2][i]=z; }

  issue(0, 0);
  bf16x8 qc[2][2], qn[2][2];
  #pragma unroll
  for (int s=0; s<2; ++s){
    qc[0][s] = *(const bf16x8*)(q00 + s*32);
    qc[1][s] = *(const bf16x8*)(q01 + s*32);
  }

  #pragma unroll 1
  for (int g=0; g<16; ++g){
    int rnd = g >> 3, c = g & 7;
    __syncthreads();                     // chunk g landed in klds[g&1]; prev reads done
    if (g < 15){
      issue((g+1)&1, (g+1)&7);           // stage next chunk (overlaps compute)
      int nkc = (g+1)&7;
      const ushort* a0 = ((g+1)>>3) ? q10 : q00;
      const ushort* a1 = ((g+1)>>3) ? q11 : q01;
      #pragma unroll
      for (int s=0; s<2; ++s){
        qn[0][s] = *(const bf16x8*)(a0 + nkc*64 + s*32);
        qn[1][s] = *(const bf16x8*)(a1 + nkc*64 + s*32);
      }
    }
    int tt = rnd*8 + wid;
    bool active = tt < 13;
    if (active){
      const ushort* kbase = &klds[g&1][0];
      #pragma unroll
      for (int s=0; s<2; ++s){
        int ru = s*4 + lg;
        #pragma unroll
        for (int ct=0; ct<13; ++ct){
          int lcol = ct*16 + l15;
          bf16x8 bfr = *(const bf16x8*)(kbase + (size_t)(lcol*8 + (ru ^ (lcol&7)))*8);
          acc[0][ct] = __builtin_amdgcn_mfma_f32_16x16x32_bf16(qc[0][s], bfr, acc[0][ct], 0,0,0);
          acc[1][ct] = __builtin_amdgcn_mfma_f32_16x16x32_bf16(qc[1][s], bfr, acc[1][ct], 0,0,0);
        }
      }
    }
    #pragma unroll
    for (int s=0; s<2; ++s){ qc[0][s] = qn[0][s]; qc[1][s] = qn[1][s]; }

    if (c == 7){                         // end of a row-pass: softmax + col-sum
      if (active){
        int rt = tt > 12 ? 12 : tt;
        #pragma unroll
        for (int e2=0; e2<2; ++e2){
          if (l15 >= 5){                 // cols 197..207 invalid
            f32x4 ninf = {-1e30f,-1e30f,-1e30f,-1e30f};
            acc[e2][12] = ninf;
          }
          if (rt==0 && lg==0){           // additive mask on query-row 0
            #pragma unroll
            for (int ct=0; ct<13; ++ct){
              int col = ct*16 + l15;
              if (col < 197) acc[e2][ct][0] += RHO_ * maskp[b*PN + col];
            }
          }
          float mrow[4], inv[4];
          #pragma unroll
          for (int r=0;r<4;++r){
            float m = acc[e2][0][r];
            #pragma unroll
            for (int ct=1; ct<13; ++ct) m = fmaxf(m, acc[e2][ct][r]);
            m = fmaxf(m, __shfl_xor(m,1));
            m = fmaxf(m, __shfl_xor(m,2));
            m = fmaxf(m, __shfl_xor(m,4));
            m = fmaxf(m, __shfl_xor(m,8));
            mrow[r] = m;
          }
          #pragma unroll
          for (int r=0;r<4;++r){
            float sm = 0.f;
            #pragma unroll
            for (int ct=0; ct<13; ++ct){
              float ev = __expf(acc[e2][ct][r] - mrow[r]);
              acc[e2][ct][r] = ev;
              sm += ev;
            }
            sm += __shfl_xor(sm,1); sm += __shfl_xor(sm,2);
            sm += __shfl_xor(sm,4); sm += __shfl_xor(sm,8);
            int prow = rt*16 + lg*4 + r;
            inv[r] = (prow < PN) ? 1.0f/sm : 0.f;
          }
          #pragma unroll
          for (int ct=0; ct<13; ++ct){
            float cs = acc[e2][ct][0]*inv[0] + acc[e2][ct][1]*inv[1]
                     + acc[e2][ct][2]*inv[2] + acc[e2][ct][3]*inv[3];
            cs += __shfl_xor(cs,16);
            cs += __shfl_xor(cs,32);
            if (lg==0) atomicAdd(&w_lds[e2][ct*16 + l15], cs);
          }
        }
      }
      if (rnd == 0){                     // reset acc for pass 2
        #pragma unroll
        for (int e2=0;e2<2;++e2)
          #pragma unroll
          for (int i=0;i<13;++i){ f32x4 z={0.f,0.f,0.f,0.f}; acc[e2][i]=z; }
      }
    }
  }
  __syncthreads();

  // phase 2: ctx[h] = (1/197) * sum_q w[q]*v[b,q,h]; thread owns h = tid
  const ushort* vb = vw + (size_t)b*PN*HH;
  float cA=0.f, cB=0.f;
  #pragma unroll 4
  for (int q=0; q<PN; ++q){
    float vq = bf2f(vb[(size_t)q*HH + tid]);
    cA += w_lds[0][q]*vq;
    cB += w_lds[1][q]*vq;
  }
  const float invP = 1.0f/197.0f;
  cA*=invP; cB*=invP;

  float sx = cA, sxx = cA*cA, sy = cB, syy = cB*cB;
  #pragma unroll
  for (int off=32; off; off>>=1){
    sx += __shfl_down(sx, off); sxx += __shfl_down(sxx, off);
    sy += __shfl_down(sy, off); syy += __shfl_down(syy, off);
  }
  if (lane==0){ red[wid*4+0]=sx; red[wid*4+1]=sxx; red[wid*4+2]=sy; red[wid*4+3]=syy; }
  __syncthreads();
  float s1A=0.f, s2A=0.f, s1B=0.f, s2B=0.f;
  #pragma unroll
  for (int w=0; w<8; ++w){
    s1A += red[w*4+0]; s2A += red[w*4+1];
    s1B += red[w*4+2]; s2B += red[w*4+3];
  }
  float muA = s1A*(1.f/512.f), muB = s1B*(1.f/512.f);
  float varA = s2A*(1.f/512.f) - muA*muA;
  float varB = s2B*(1.f/512.f) - muB*muB;
  float rsA = rsqrtf(varA + 1e-5f), rsB = rsqrtf(varB + 1e-5f);

  int h = tid;
  float g0=lng[h], bb0=lnb[h];
  float dA = ((cA-muA)*rsA*g0 + bb0) * cls_fc[(size_t)e0*HH + h];
  float dB = ((cB-muB)*rsB*g0 + bb0) * cls_fc[(size_t)(e0+1)*HH + h];

  // g2g: 768 dims over 512 threads
  dA += mcls[b*DIN + tid]*ecls[(size_t)e0*DIN + tid];
  dB += mcls[b*DIN + tid]*ecls[(size_t)(e0+1)*DIN + tid];
  if (tid < 256){
    int j = tid + 512;
    dA += mcls[b*DIN + j]*ecls[(size_t)e0*DIN + j];
    dB += mcls[b*DIN + j]*ecls[(size_t)(e0+1)*DIN + j];
  }

  __syncthreads();
  #pragma unroll
  for (int off=32; off; off>>=1){ dA += __shfl_down(dA, off); dB += __shfl_down(dB, off); }
  if (lane==0){ red[wid*2+0]=dA; red[wid*2+1]=dB; }
  __syncthreads();
  if (tid==0){
    float oA=0.f, oB=0.f;
    #pragma unroll
    for (int w=0; w<8; ++w){ oA += red[w*2+0]; oB += red[w*2+1]; }
    outp[b*EN + e0]   = 0.5f*oA;
    outp[b*EN + e0+1] = 0.5f*oB;
  }
}

extern "C" void kernel_launch(void* const* d_in, const int* in_sizes, int n_in,
                              void* d_out, int out_size, void* d_ws, size_t ws_size,
                              hipStream_t stream)
{
  (void)in_sizes; (void)n_in; (void)out_size; (void)ws_size;
  const float* ecls = (const float*)d_in[0];
  const float* etok = (const float*)d_in[1];
  const float* mcls = (const float*)d_in[2];
  const float* mtok = (const float*)d_in[3];
  const float* maskp= (const float*)d_in[4];
  const float* Wq   = (const float*)d_in[5];
  const float* bq   = (const float*)d_in[6];
  const float* Wk   = (const float*)d_in[7];
  const float* bk   = (const float*)d_in[8];
  const float* Wv   = (const float*)d_in[9];
  const float* bv   = (const float*)d_in[10];
  const float* Wc   = (const float*)d_in[11];
  const float* bc   = (const float*)d_in[12];
  const float* lng  = (const float*)d_in[13];
  const float* lnb  = (const float*)d_in[14];

  char* ws = (char*)d_ws;
  size_t off = 0;
  auto take = [&](size_t bytes){ char* p = ws + off; off += (bytes + 255) & ~(size_t)255; return p; };
  ushort* a_ent = (ushort*)take((size_t)EN*PN*DIN*2);
  ushort* a_men = (ushort*)take((size_t)BN*PN*DIN*2);
  ushort* a_cls = (ushort*)take((size_t)EN*DIN*2);
  ushort* Wt    = (ushort*)take((size_t)4*HH*DIN*2);
  float*  bq_s  = (float*)take((size_t)HH*4);
  ushort* qo    = (ushort*)take((size_t)EN*PN*HH*2);
  ushort* ko    = (ushort*)take((size_t)BN*PN*HH*2);
  ushort* vo    = (ushort*)take((size_t)BN*PN*HH*2);
  float*  co    = (float*)take((size_t)EN*HH*4);

  prep_kernel<<<1024, 256, 0, stream>>>(etok, mtok, ecls, bq, a_ent, a_men, a_cls, bq_s);
  w_transpose<<<dim3(12,8,4), 256, 0, stream>>>(Wq, Wk, Wv, Wc, Wt);
  gemm_proj<<<dim3(200,4,1), 256, 0, stream>>>(a_ent, a_men, a_cls, Wt,
                                               bq_s, bk, bv, bc, qo, ko, vo, co);
  attn_kernel<<<1024, 512, 0, stream>>>(qo, ko, vo, co, maskp, mcls, ecls,
                                        lng, lnb, (float*)d_out);
}